// Round 1
// baseline (1093.920 us; speedup 1.0000x reference)
//
#include <hip/hip_runtime.h>
#include <math.h>
#include <float.h>

#define NPTS   32768
#define NCODES 8192
#define D      64
#define HWSZ   4096
#define KSPLIT 4
#define KPER   (NCODES / KSPLIT)   // 2048
#define TILE   128

#define DECAY_F 0.99f
#define OMD_F   ((float)(1.0 - 0.99))   // match python's 1.0-0.99 rounded to f32
#define EPS_F   1e-5f

// ---- d_out layout (floats) ----
#define ZQ_OFF    0
#define CODES_OFF 2097152
#define NE_OFF    2129920
#define NCS_OFF   2654208
#define NEA_OFF   2662400

// ---- workspace layout (floats) ----
#define WS_E2    0        // 8192
#define WS_CSB   8192     // 8192
#define WS_ESUM  16384    // 524288
#define WS_NSUM  540672   // 64 (padded)
#define WS_CODES 540736   // 32768 (int)
#define WS_PSC   573504   // KSPLIT*32768
#define WS_PIX   704576   // KSPLIT*32768 (int)

// e2[k] = sum_d embed[k][d]^2 ; one wave per code
__global__ void k_e2(const float* __restrict__ embed, float* __restrict__ e2arr) {
    int k = blockIdx.x * 4 + (threadIdx.x >> 6);
    int lane = threadIdx.x & 63;
    float v = embed[k * D + lane];
    float s = v * v;
    s += __shfl_xor(s, 32);
    s += __shfl_xor(s, 16);
    s += __shfl_xor(s, 8);
    s += __shfl_xor(s, 4);
    s += __shfl_xor(s, 2);
    s += __shfl_xor(s, 1);
    if (lane == 0) e2arr[k] = s;
}

// Partial argmin: each block = 256 points x KPER codes (one K-split).
__global__ __launch_bounds__(256) void k_argmin(
    const float* __restrict__ z, const float* __restrict__ embed,
    const float* __restrict__ e2arr,
    float* __restrict__ pscore, int* __restrict__ pidx)
{
    __shared__ float et[TILE * D];  // 32 KiB
    const int tid = threadIdx.x;
    const int pb = blockIdx.x & 127;
    const int split = blockIdx.x >> 7;
    const int n = pb * 256 + tid;
    const int b = n >> 12;
    const int hw = n & 4095;
    const float* zb = z + (size_t)b * D * HWSZ + hw;

    float x[D];
#pragma unroll
    for (int c = 0; c < D; ++c) x[c] = zb[c * HWSZ];  // coalesced per c
    float x2 = 0.f;
#pragma unroll
    for (int c = 0; c < D; ++c) x2 += x[c] * x[c];

    float bestv = FLT_MAX;
    int bestk = 0;
    const int kbase = split * KPER;

    for (int t = 0; t < KPER; t += TILE) {
        __syncthreads();
        {
            const float4* src = (const float4*)(embed + (size_t)(kbase + t) * D);
            float4* dst = (float4*)et;
#pragma unroll
            for (int i = 0; i < (TILE * D / 4) / 256; ++i)
                dst[tid + i * 256] = src[tid + i * 256];
        }
        __syncthreads();

        for (int k = 0; k < TILE; k += 4) {
            const float4* r0 = (const float4*)(et + (k + 0) * D);
            const float4* r1 = (const float4*)(et + (k + 1) * D);
            const float4* r2 = (const float4*)(et + (k + 2) * D);
            const float4* r3 = (const float4*)(et + (k + 3) * D);
            float a0 = 0.f, a1 = 0.f, a2 = 0.f, a3 = 0.f;  // even-d4 partials
            float c0 = 0.f, c1 = 0.f, c2 = 0.f, c3 = 0.f;  // odd-d4 partials
#pragma unroll
            for (int d4 = 0; d4 < 16; ++d4) {
                float4 e0 = r0[d4], e1 = r1[d4], e2v = r2[d4], e3 = r3[d4];
                float xx0 = x[4 * d4 + 0], xx1 = x[4 * d4 + 1];
                float xx2 = x[4 * d4 + 2], xx3 = x[4 * d4 + 3];
                if ((d4 & 1) == 0) {
                    a0 += xx0 * e0.x; a0 += xx1 * e0.y; a0 += xx2 * e0.z; a0 += xx3 * e0.w;
                    a1 += xx0 * e1.x; a1 += xx1 * e1.y; a1 += xx2 * e1.z; a1 += xx3 * e1.w;
                    a2 += xx0 * e2v.x; a2 += xx1 * e2v.y; a2 += xx2 * e2v.z; a2 += xx3 * e2v.w;
                    a3 += xx0 * e3.x; a3 += xx1 * e3.y; a3 += xx2 * e3.z; a3 += xx3 * e3.w;
                } else {
                    c0 += xx0 * e0.x; c0 += xx1 * e0.y; c0 += xx2 * e0.z; c0 += xx3 * e0.w;
                    c1 += xx0 * e1.x; c1 += xx1 * e1.y; c1 += xx2 * e1.z; c1 += xx3 * e1.w;
                    c2 += xx0 * e2v.x; c2 += xx1 * e2v.y; c2 += xx2 * e2v.z; c2 += xx3 * e2v.w;
                    c3 += xx0 * e3.x; c3 += xx1 * e3.y; c3 += xx2 * e3.z; c3 += xx3 * e3.w;
                }
            }
            const int kk = kbase + t + k;
            float s0 = x2 + e2arr[kk + 0] - 2.f * (a0 + c0);
            float s1 = x2 + e2arr[kk + 1] - 2.f * (a1 + c1);
            float s2 = x2 + e2arr[kk + 2] - 2.f * (a2 + c2);
            float s3 = x2 + e2arr[kk + 3] - 2.f * (a3 + c3);
            if (s0 < bestv) { bestv = s0; bestk = kk + 0; }
            if (s1 < bestv) { bestv = s1; bestk = kk + 1; }
            if (s2 < bestv) { bestv = s2; bestk = kk + 2; }
            if (s3 < bestv) { bestv = s3; bestk = kk + 3; }
        }
    }
    pscore[split * NPTS + n] = bestv;
    pidx[split * NPTS + n] = bestk;
}

// Combine K-splits (ascending split order keeps lowest index on ties)
__global__ void k_final(const float* __restrict__ pscore, const int* __restrict__ pidx,
                        int* __restrict__ codes_i, float* __restrict__ out_codes)
{
    int n = blockIdx.x * 256 + threadIdx.x;
    float bv = pscore[n];
    int bk = pidx[n];
#pragma unroll
    for (int s = 1; s < KSPLIT; ++s) {
        float v = pscore[s * NPTS + n];
        int k = pidx[s * NPTS + n];
        if (v < bv) { bv = v; bk = k; }
    }
    codes_i[n] = bk;
    out_codes[n] = (float)bk;
}

// z_q gather + segment-sum scatters
__global__ __launch_bounds__(256) void k_gather(
    const float* __restrict__ z, const float* __restrict__ embed,
    const int* __restrict__ codes_i, float* __restrict__ zq,
    float* __restrict__ csb, float* __restrict__ esum)
{
    int n = blockIdx.x * 256 + threadIdx.x;
    int b = n >> 12, hw = n & 4095;
    int code = codes_i[n];
    atomicAdd(&csb[code], 1.0f);
    const float* er = embed + (size_t)code * D;
    size_t zoff = (size_t)b * D * HWSZ + hw;
#pragma unroll 4
    for (int c = 0; c < D; ++c) {
        float xv = z[zoff + (size_t)c * HWSZ];
        zq[zoff + (size_t)c * HWSZ] = er[c];
        atomicAdd(&esum[code * D + c], xv);
    }
}

// new_cluster_size + global sum n
__global__ void k_cs(const float* __restrict__ cs, const float* __restrict__ csb,
                     float* __restrict__ out_ncs, float* __restrict__ nsum)
{
    int k = blockIdx.x * 256 + threadIdx.x;
    float v = cs[k] * DECAY_F + csb[k] * OMD_F;
    out_ncs[k] = v;
    float t = v;
    t += __shfl_xor(t, 32);
    t += __shfl_xor(t, 16);
    t += __shfl_xor(t, 8);
    t += __shfl_xor(t, 4);
    t += __shfl_xor(t, 2);
    t += __shfl_xor(t, 1);
    if ((threadIdx.x & 63) == 0) atomicAdd(nsum, t);
}

// new_embed_avg + normalized new_embed ; one wave per code
__global__ void k_upd(const float* __restrict__ eavg, const float* __restrict__ esum,
                      const float* __restrict__ ncs, const float* __restrict__ nsum,
                      float* __restrict__ out_nea, float* __restrict__ out_ne)
{
    int k = blockIdx.x * 4 + (threadIdx.x >> 6);
    int lane = threadIdx.x & 63;
    int idx = k * D + lane;
    float ea = eavg[idx] * DECAY_F + esum[idx] * OMD_F;
    out_nea[idx] = ea;
    float n = *nsum;
    float csm = (ncs[k] + EPS_F) / (n + (float)NCODES * EPS_F) * n;
    float v = ea / csm;
    float s = v * v;
    s += __shfl_xor(s, 32);
    s += __shfl_xor(s, 16);
    s += __shfl_xor(s, 8);
    s += __shfl_xor(s, 4);
    s += __shfl_xor(s, 2);
    s += __shfl_xor(s, 1);
    out_ne[idx] = v / sqrtf(s);
}

extern "C" void kernel_launch(void* const* d_in, const int* in_sizes, int n_in,
                              void* d_out, int out_size, void* d_ws, size_t ws_size,
                              hipStream_t stream) {
    const float* z     = (const float*)d_in[0];
    const float* embed = (const float*)d_in[1];
    const float* cs    = (const float*)d_in[2];
    const float* eavg  = (const float*)d_in[3];

    float* out = (float*)d_out;
    float* zq        = out + ZQ_OFF;
    float* out_codes = out + CODES_OFF;
    float* out_ne    = out + NE_OFF;
    float* out_ncs   = out + NCS_OFF;
    float* out_nea   = out + NEA_OFF;

    float* ws = (float*)d_ws;
    float* e2arr  = ws + WS_E2;
    float* csb    = ws + WS_CSB;
    float* esum   = ws + WS_ESUM;
    float* nsum   = ws + WS_NSUM;
    int*   codesi = (int*)(ws + WS_CODES);
    float* psc    = ws + WS_PSC;
    int*   pix    = (int*)(ws + WS_PIX);

    // zero csb + esum + nsum (contiguous region), graph-capture safe
    hipMemsetAsync((char*)d_ws + (size_t)WS_CSB * sizeof(float), 0,
                   (size_t)(WS_NSUM + 64 - WS_CSB) * sizeof(float), stream);

    k_e2<<<NCODES / 4, 256, 0, stream>>>(embed, e2arr);
    k_argmin<<<(NPTS / 256) * KSPLIT, 256, 0, stream>>>(z, embed, e2arr, psc, pix);
    k_final<<<NPTS / 256, 256, 0, stream>>>(psc, pix, codesi, out_codes);
    k_gather<<<NPTS / 256, 256, 0, stream>>>(z, embed, codesi, zq, csb, esum);
    k_cs<<<NCODES / 256, 256, 0, stream>>>(cs, csb, out_ncs, nsum);
    k_upd<<<NCODES / 4, 256, 0, stream>>>(eavg, esum, out_ncs, nsum, out_nea, out_ne);
}

// Round 2
// 596.928 us; speedup vs baseline: 1.8326x; 1.8326x over previous
//
#include <hip/hip_runtime.h>
#include <math.h>
#include <float.h>

#define NPTS   32768
#define NCODES 8192
#define D      64
#define HWSZ   4096

#define TP 64                 // points per block
#define TQ 512                // codes per tile
#define NT (NCODES / TQ)      // 16 tiles
#define DC 8                  // dims per chunk
#define NSTEP (NT * (D / DC)) // 128

#define DECAY_F 0.99f
#define OMD_F   ((float)(1.0 - 0.99))
#define EPS_F   1e-5f

// ---- d_out layout (floats) ----
#define ZQ_OFF    0
#define CODES_OFF 2097152
#define NE_OFF    2129920
#define NCS_OFF   2654208
#define NEA_OFF   2662400

// ---- workspace layout (floats) ----
#define WS_E2    0        // 8192
#define WS_CSB   8192     // 8192
#define WS_EMBT  16384    // 524288 : embed_T during argmin, esum afterwards
#define WS_NSUM  540672   // 64
#define WS_CODES 540736   // 32768 (int)

// embed (8192x64) -> embed_T (64x8192)
__global__ void k_transpose(const float* __restrict__ embed, float* __restrict__ embT) {
    int idx = blockIdx.x * 256 + threadIdx.x;   // float4 slot, 131072 total
    int k = idx >> 4;
    int dq = idx & 15;
    float4 v = *(const float4*)(embed + (size_t)k * D + dq * 4);
    embT[(size_t)(dq * 4 + 0) * NCODES + k] = v.x;
    embT[(size_t)(dq * 4 + 1) * NCODES + k] = v.y;
    embT[(size_t)(dq * 4 + 2) * NCODES + k] = v.z;
    embT[(size_t)(dq * 4 + 3) * NCODES + k] = v.w;
}

// e2[k] = sum_d embed[k][d]^2 ; one wave per code
__global__ void k_e2(const float* __restrict__ embed, float* __restrict__ e2arr) {
    int k = blockIdx.x * 4 + (threadIdx.x >> 6);
    int lane = threadIdx.x & 63;
    float v = embed[k * D + lane];
    float s = v * v;
    s += __shfl_xor(s, 32);
    s += __shfl_xor(s, 16);
    s += __shfl_xor(s, 8);
    s += __shfl_xor(s, 4);
    s += __shfl_xor(s, 2);
    s += __shfl_xor(s, 1);
    if (lane == 0) e2arr[k] = s;
}

// GEMM-tiled argmin: block = 64 points x all codes (tiles of 512).
// Thread: 8 points (pi) x 16 codes (qi, two groups of 8, 256 apart).
__global__ __launch_bounds__(256, 2) void k_argmin(
    const float* __restrict__ z, const float* __restrict__ embT,
    const float* __restrict__ e2arr,
    int* __restrict__ codes_i, float* __restrict__ out_codes)
{
    __shared__ float xt[D * TP];         // [dim][pt] 16 KB
    __shared__ float et[2 * DC * TQ];    // double-buffered e chunk, 32 KB
    __shared__ float redv[4 * TP];
    __shared__ int   redi[4 * TP];

    const int tid = threadIdx.x;
    const int pi  = tid & 7;
    const int qi  = tid >> 3;     // 0..31
    const int lane = tid & 63;
    const int wave = tid >> 6;
    const int n0  = blockIdx.x * TP;
    const int b   = n0 >> 12;
    const int hw0 = n0 & 4095;
    const int pi8 = pi * 8;
    const int qi8 = qi * 8;

    // stage x tile (all 64 dims x 64 pts) + e chunk 0
    {
        const float* zb = z + (size_t)b * D * HWSZ + hw0;
#pragma unroll
        for (int i = 0; i < 4; ++i) {
            int s = tid + i * 256;
            int d = s >> 4, c4 = s & 15;
            float4 v = *(const float4*)(zb + (size_t)d * HWSZ + c4 * 4);
            *(float4*)(xt + d * TP + c4 * 4) = v;
        }
#pragma unroll
        for (int i = 0; i < 4; ++i) {
            int s = tid + i * 256;
            int row = s >> 7, c4 = s & 127;
            float4 v = *(const float4*)(embT + (size_t)row * NCODES + c4 * 4);
            *(float4*)(et + row * TQ + c4 * 4) = v;
        }
    }
    __syncthreads();

    float acc[8][16];
    float bestv[8]; int besti[8];
#pragma unroll
    for (int p = 0; p < 8; ++p) { bestv[p] = FLT_MAX; besti[p] = 0; }

    for (int cs = 0; cs < NSTEP; ++cs) {
        const int t = cs >> 3, dc = cs & 7;

        // prefetch next e chunk into registers (hidden under compute)
        float4 pr[4];
        const bool pf = (cs + 1 < NSTEP);
        if (pf) {
            const int t2 = (cs + 1) >> 3, dc2 = (cs + 1) & 7;
            const float* gsrc = embT + (size_t)(dc2 * DC) * NCODES + t2 * TQ;
#pragma unroll
            for (int i = 0; i < 4; ++i) {
                int s = tid + i * 256;
                int row = s >> 7, c4 = s & 127;
                pr[i] = *(const float4*)(gsrc + (size_t)row * NCODES + c4 * 4);
            }
        }
        // issue e2 loads early for epilogue steps
        float4 e2a0, e2a1, e2b0, e2b1;
        if (dc == 7) {
            const float* e2p = e2arr + t * TQ;
            e2a0 = *(const float4*)(e2p + qi8);
            e2a1 = *(const float4*)(e2p + qi8 + 4);
            e2b0 = *(const float4*)(e2p + 256 + qi8);
            e2b1 = *(const float4*)(e2p + 256 + qi8 + 4);
        }
        if (dc == 0) {
#pragma unroll
            for (int p = 0; p < 8; ++p)
#pragma unroll
                for (int q = 0; q < 16; ++q) acc[p][q] = 0.f;
        }

        const float* ebuf = et + (cs & 1) * (DC * TQ);
        const float* xb   = xt + dc * DC * TP;
#pragma unroll 2
        for (int d = 0; d < DC; ++d) {
            float4 xa  = *(const float4*)(xb + d * TP + pi8);
            float4 xc  = *(const float4*)(xb + d * TP + pi8 + 4);
            float4 ea0 = *(const float4*)(ebuf + d * TQ + qi8);
            float4 ea1 = *(const float4*)(ebuf + d * TQ + qi8 + 4);
            float4 eb0 = *(const float4*)(ebuf + d * TQ + 256 + qi8);
            float4 eb1 = *(const float4*)(ebuf + d * TQ + 256 + qi8 + 4);
            float xv[8]  = {xa.x, xa.y, xa.z, xa.w, xc.x, xc.y, xc.z, xc.w};
            float ev[16] = {ea0.x, ea0.y, ea0.z, ea0.w, ea1.x, ea1.y, ea1.z, ea1.w,
                            eb0.x, eb0.y, eb0.z, eb0.w, eb1.x, eb1.y, eb1.z, eb1.w};
#pragma unroll
            for (int p = 0; p < 8; ++p)
#pragma unroll
                for (int q = 0; q < 16; ++q)
                    acc[p][q] = fmaf(xv[p], ev[q], acc[p][q]);
        }

        if (dc == 7) {
            float e2v[16] = {e2a0.x, e2a0.y, e2a0.z, e2a0.w, e2a1.x, e2a1.y, e2a1.z, e2a1.w,
                             e2b0.x, e2b0.y, e2b0.z, e2b0.w, e2b1.x, e2b1.y, e2b1.z, e2b1.w};
            const int base = t * TQ;
#pragma unroll
            for (int q = 0; q < 16; ++q) {
                const int idx = base + (q >> 3) * 256 + qi8 + (q & 7);
                const float ee = e2v[q];
#pragma unroll
                for (int p = 0; p < 8; ++p) {
                    float sc = fmaf(-2.f, acc[p][q], ee);
                    if (sc < bestv[p]) { bestv[p] = sc; besti[p] = idx; }
                }
            }
        }

        // write prefetched chunk into the other buffer; one barrier per step
        if (pf) {
            float* ebn = et + ((cs + 1) & 1) * (DC * TQ);
#pragma unroll
            for (int i = 0; i < 4; ++i) {
                int s = tid + i * 256;
                int row = s >> 7, c4 = s & 127;
                *(float4*)(ebn + row * TQ + c4 * 4) = pr[i];
            }
        }
        __syncthreads();
    }

    // reduce across qi: butterfly over lane bits 3,4,5 (value, then index tiebreak)
#pragma unroll
    for (int p = 0; p < 8; ++p) {
        float v; int j;
        v = __shfl_xor(bestv[p], 8);  j = __shfl_xor(besti[p], 8);
        if (v < bestv[p] || (v == bestv[p] && j < besti[p])) { bestv[p] = v; besti[p] = j; }
        v = __shfl_xor(bestv[p], 16); j = __shfl_xor(besti[p], 16);
        if (v < bestv[p] || (v == bestv[p] && j < besti[p])) { bestv[p] = v; besti[p] = j; }
        v = __shfl_xor(bestv[p], 32); j = __shfl_xor(besti[p], 32);
        if (v < bestv[p] || (v == bestv[p] && j < besti[p])) { bestv[p] = v; besti[p] = j; }
    }
    if (lane < 8) {
#pragma unroll
        for (int p = 0; p < 8; ++p) {
            redv[wave * TP + lane * 8 + p] = bestv[p];
            redi[wave * TP + lane * 8 + p] = besti[p];
        }
    }
    __syncthreads();
    if (tid < TP) {
        float bv = redv[tid]; int bi = redi[tid];
#pragma unroll
        for (int w = 1; w < 4; ++w) {
            float v = redv[w * TP + tid]; int j = redi[w * TP + tid];
            if (v < bv || (v == bv && j < bi)) { bv = v; bi = j; }
        }
        codes_i[n0 + tid] = bi;
        out_codes[n0 + tid] = (float)bi;
    }
}

// z_q gather + segment-sum scatters
__global__ __launch_bounds__(256) void k_gather(
    const float* __restrict__ z, const float* __restrict__ embed,
    const int* __restrict__ codes_i, float* __restrict__ zq,
    float* __restrict__ csb, float* __restrict__ esum)
{
    int n = blockIdx.x * 256 + threadIdx.x;
    int b = n >> 12, hw = n & 4095;
    int code = codes_i[n];
    atomicAdd(&csb[code], 1.0f);
    const float* er = embed + (size_t)code * D;
    size_t zoff = (size_t)b * D * HWSZ + hw;
#pragma unroll 4
    for (int c = 0; c < D; ++c) {
        float xv = z[zoff + (size_t)c * HWSZ];
        zq[zoff + (size_t)c * HWSZ] = er[c];
        atomicAdd(&esum[code * D + c], xv);
    }
}

// new_cluster_size + global sum n
__global__ void k_cs(const float* __restrict__ cs, const float* __restrict__ csb,
                     float* __restrict__ out_ncs, float* __restrict__ nsum)
{
    int k = blockIdx.x * 256 + threadIdx.x;
    float v = cs[k] * DECAY_F + csb[k] * OMD_F;
    out_ncs[k] = v;
    float t = v;
    t += __shfl_xor(t, 32);
    t += __shfl_xor(t, 16);
    t += __shfl_xor(t, 8);
    t += __shfl_xor(t, 4);
    t += __shfl_xor(t, 2);
    t += __shfl_xor(t, 1);
    if ((threadIdx.x & 63) == 0) atomicAdd(nsum, t);
}

// new_embed_avg + normalized new_embed ; one wave per code
__global__ void k_upd(const float* __restrict__ eavg, const float* __restrict__ esum,
                      const float* __restrict__ ncs, const float* __restrict__ nsum,
                      float* __restrict__ out_nea, float* __restrict__ out_ne)
{
    int k = blockIdx.x * 4 + (threadIdx.x >> 6);
    int lane = threadIdx.x & 63;
    int idx = k * D + lane;
    float ea = eavg[idx] * DECAY_F + esum[idx] * OMD_F;
    out_nea[idx] = ea;
    float n = *nsum;
    float csm = (ncs[k] + EPS_F) / (n + (float)NCODES * EPS_F) * n;
    float v = ea / csm;
    float s = v * v;
    s += __shfl_xor(s, 32);
    s += __shfl_xor(s, 16);
    s += __shfl_xor(s, 8);
    s += __shfl_xor(s, 4);
    s += __shfl_xor(s, 2);
    s += __shfl_xor(s, 1);
    out_ne[idx] = v / sqrtf(s);
}

extern "C" void kernel_launch(void* const* d_in, const int* in_sizes, int n_in,
                              void* d_out, int out_size, void* d_ws, size_t ws_size,
                              hipStream_t stream) {
    const float* z     = (const float*)d_in[0];
    const float* embed = (const float*)d_in[1];
    const float* cs    = (const float*)d_in[2];
    const float* eavg  = (const float*)d_in[3];

    float* out = (float*)d_out;
    float* zq        = out + ZQ_OFF;
    float* out_codes = out + CODES_OFF;
    float* out_ne    = out + NE_OFF;
    float* out_ncs   = out + NCS_OFF;
    float* out_nea   = out + NEA_OFF;

    float* ws = (float*)d_ws;
    float* e2arr  = ws + WS_E2;
    float* csb    = ws + WS_CSB;
    float* embT   = ws + WS_EMBT;   // doubles as esum after argmin
    float* esum   = ws + WS_EMBT;
    float* nsum   = ws + WS_NSUM;
    int*   codesi = (int*)(ws + WS_CODES);

    hipMemsetAsync((char*)d_ws + (size_t)WS_CSB * sizeof(float), 0, 8192 * sizeof(float), stream);
    hipMemsetAsync((char*)d_ws + (size_t)WS_NSUM * sizeof(float), 0, 64 * sizeof(float), stream);

    k_transpose<<<512, 256, 0, stream>>>(embed, embT);
    k_e2<<<NCODES / 4, 256, 0, stream>>>(embed, e2arr);
    k_argmin<<<NPTS / TP, 256, 0, stream>>>(z, embT, e2arr, codesi, out_codes);

    // embed_T no longer needed: zero the region for esum accumulation
    hipMemsetAsync((char*)d_ws + (size_t)WS_EMBT * sizeof(float), 0, 524288 * sizeof(float), stream);

    k_gather<<<NPTS / 256, 256, 0, stream>>>(z, embed, codesi, zq, csb, esum);
    k_cs<<<NCODES / 256, 256, 0, stream>>>(cs, csb, out_ncs, nsum);
    k_upd<<<NCODES / 4, 256, 0, stream>>>(eavg, esum, out_ncs, nsum, out_nea, out_ne);
}

// Round 4
// 343.431 us; speedup vs baseline: 3.1853x; 1.7381x over previous
//
#include <hip/hip_runtime.h>
#include <math.h>
#include <float.h>

#define NPTS   32768
#define NCODES 8192
#define D      64
#define HWSZ   4096
#define KSPLIT 4

#define DECAY_F 0.99f
#define OMD_F   ((float)(1.0 - 0.99))
#define EPS_F   1e-5f

typedef __attribute__((ext_vector_type(8))) short bf16x8;
typedef __attribute__((ext_vector_type(8))) unsigned short us8;
typedef __attribute__((ext_vector_type(4))) float f32x4;

// ---- d_out layout (floats) ----
#define ZQ_OFF    0
#define CODES_OFF 2097152
#define NE_OFF    2129920
#define NCS_OFF   2654208
#define NEA_OFF   2662400

// ---- workspace layout (floats) ----
#define WS_CSB   0         // 8192
#define WS_NSUM  8192      // 64
#define WS_ESUM  8256      // 524288
#define WS_CODES 532544    // 32768 (int)
#define WS_PB1I  565312    // 4*32768 (int)
#define WS_PB2I  696384    // 4*32768 (int)
#define WS_ME2   827456    // 8192
#define WS_EB    835648    // 3 planes, 1MB (262144 floats) apart
#define WS_ZB    1622080   // 3 planes, 4MB (1048576 floats) apart

__device__ __forceinline__ unsigned short f2bf(float x) {
    unsigned int u = __float_as_uint(x);
    unsigned int r = (u + 0x7fffu + ((u >> 16) & 1u)) >> 16;
    return (unsigned short)r;
}
__device__ __forceinline__ float bf2f(unsigned short b) {
    return __uint_as_float(((unsigned int)b) << 16);
}

// embed f32 [8192][64] -> 3 bf16 planes in stage-blocked K-major layout
// element (code c, dim d) -> plane[(c>>7)*8192 + (d>>3)*1024 + (c&127)*8 + (d&7)]
// plus me2[c] = -0.5 * sum_d e^2
__global__ void k_prep_e(const float* __restrict__ embed,
                         unsigned short* __restrict__ eb0, unsigned short* __restrict__ eb1,
                         unsigned short* __restrict__ eb2, float* __restrict__ me2) {
    int c = blockIdx.x * 256 + threadIdx.x;
    const float4* src = (const float4*)(embed + (size_t)c * D);
    float row[64];
    float s2 = 0.f;
#pragma unroll
    for (int i = 0; i < 16; ++i) {
        float4 v = src[i];
        row[i * 4 + 0] = v.x; row[i * 4 + 1] = v.y;
        row[i * 4 + 2] = v.z; row[i * 4 + 3] = v.w;
        s2 += v.x * v.x; s2 += v.y * v.y; s2 += v.z * v.z; s2 += v.w * v.w;
    }
    size_t base = (size_t)(c >> 7) * 8192 + (size_t)(c & 127) * 8;
#pragma unroll
    for (int s = 0; s < 8; ++s) {
        us8 v0, v1, v2;
#pragma unroll
        for (int j = 0; j < 8; ++j) {
            float x = row[s * 8 + j];
            unsigned short a = f2bf(x);  float fa = bf2f(a);
            float r1 = x - fa;
            unsigned short b = f2bf(r1); float fb = bf2f(b);
            float r2 = r1 - fb;
            unsigned short cc = f2bf(r2);
            v0[j] = a; v1[j] = b; v2[j] = cc;
        }
        *(us8*)(eb0 + base + (size_t)s * 1024) = v0;
        *(us8*)(eb1 + base + (size_t)s * 1024) = v1;
        *(us8*)(eb2 + base + (size_t)s * 1024) = v2;
    }
    me2[c] = -0.5f * s2;
}

// z f32 [8][64][4096] -> 3 bf16 planes [pt][dim] (rows of 64)
__global__ void k_prep_z(const float* __restrict__ z,
                         unsigned short* __restrict__ zb0, unsigned short* __restrict__ zb1,
                         unsigned short* __restrict__ zb2) {
    int n = blockIdx.x * 256 + threadIdx.x;
    int b = n >> 12, hw = n & 4095;
    const float* zp = z + (size_t)b * D * HWSZ + hw;
    float row[64];
#pragma unroll
    for (int c = 0; c < 64; ++c) row[c] = zp[(size_t)c * HWSZ];
#pragma unroll
    for (int s = 0; s < 8; ++s) {
        us8 v0, v1, v2;
#pragma unroll
        for (int j = 0; j < 8; ++j) {
            float x = row[s * 8 + j];
            unsigned short a = f2bf(x);  float fa = bf2f(a);
            float r1 = x - fa;
            unsigned short b2 = f2bf(r1); float fb = bf2f(b2);
            float r2 = r1 - fb;
            unsigned short cc = f2bf(r2);
            v0[j] = a; v1[j] = b2; v2[j] = cc;
        }
        *(us8*)(zb0 + (size_t)n * 64 + s * 8) = v0;
        *(us8*)(zb1 + (size_t)n * 64 + s * 8) = v1;
        *(us8*)(zb2 + (size_t)n * 64 + s * 8) = v2;
    }
}

#define MFMA16 __builtin_amdgcn_mfma_f32_16x16x32_bf16
#define PAIR(a, b)                                      \
    acc0 = MFMA16(ea[a][0], zf[0][b][0], acc0, 0, 0, 0); \
    acc1 = MFMA16(ea[a][0], zf[1][b][0], acc1, 0, 0, 0); \
    acc2 = MFMA16(ea[a][0], zf[2][b][0], acc2, 0, 0, 0); \
    acc3 = MFMA16(ea[a][0], zf[3][b][0], acc3, 0, 0, 0); \
    acc0 = MFMA16(ea[a][1], zf[0][b][1], acc0, 0, 0, 0); \
    acc1 = MFMA16(ea[a][1], zf[1][b][1], acc1, 0, 0, 0); \
    acc2 = MFMA16(ea[a][1], zf[2][b][1], acc2, 0, 0, 0); \
    acc3 = MFMA16(ea[a][1], zf[3][b][1], acc3, 0, 0, 0);

// MFMA argmin: block = 256 pts x 2048 codes (one split).
// Wave = 64 pts (4 N-tiles of 16); A = embed tile from LDS, B = z in regs.
// Tracks TOP-2 (m = dot - 0.5*e2) per point per split; exact fp32 refine follows.
__global__ __launch_bounds__(256, 2) void k_argmin_mfma(
    const unsigned short* __restrict__ eb0, const unsigned short* __restrict__ eb1,
    const unsigned short* __restrict__ eb2,
    const unsigned short* __restrict__ zb0, const unsigned short* __restrict__ zb1,
    const unsigned short* __restrict__ zb2,
    const float* __restrict__ me2g,
    int* __restrict__ pb1i, int* __restrict__ pb2i)
{
    __shared__ unsigned short ets[3 * 8192];   // 48KB: [lvl][slot(8)][ci(128)][8 bf16]
    __shared__ float me2s[128];

    const int tid = threadIdx.x;
    const int l = tid & 63;
    const int w = tid >> 6;
    const int l15 = l & 15;
    const int hi4 = l >> 4;
    const int split = blockIdx.x >> 7;
    const int pgrp  = blockIdx.x & 127;
    const int ptw   = pgrp * 256 + w * 64;

    // B fragments: z for this wave's 64 points, 3 levels, K=64 in 2 chunks of 32
    bf16x8 zf[4][3][2];
#pragma unroll
    for (int m = 0; m < 4; ++m) {
        const size_t roff = (size_t)(ptw + m * 16 + l15) * 64;
#pragma unroll
        for (int kc = 0; kc < 2; ++kc) {
            zf[m][0][kc] = *(const bf16x8*)(zb0 + roff + kc * 32 + hi4 * 8);
            zf[m][1][kc] = *(const bf16x8*)(zb1 + roff + kc * 32 + hi4 * 8);
            zf[m][2][kc] = *(const bf16x8*)(zb2 + roff + kc * 32 + hi4 * 8);
        }
    }

    float b1m[4], b2m[4]; int b1i[4], b2i[4];
#pragma unroll
    for (int m = 0; m < 4; ++m) { b1m[m] = -FLT_MAX; b2m[m] = -FLT_MAX; b1i[m] = 0; b2i[m] = 0; }

    for (int stg = 0; stg < 16; ++stg) {
        const int sg = split * 16 + stg;
        const int codebase = sg * 128;
        __syncthreads();
        {
            const char* s0 = (const char*)eb0 + (size_t)sg * 16384;
            const char* s1 = (const char*)eb1 + (size_t)sg * 16384;
            const char* s2 = (const char*)eb2 + (size_t)sg * 16384;
            float4 tmp[12];
#pragma unroll
            for (int i = 0; i < 12; ++i) {
                int c = w * 12 + i;
                int lvl = c >> 4;
                const char* sp = (lvl == 0) ? s0 : ((lvl == 1) ? s1 : s2);
                tmp[i] = *(const float4*)(sp + (size_t)(c & 15) * 1024 + l * 16);
            }
#pragma unroll
            for (int i = 0; i < 12; ++i) {
                int c = w * 12 + i;
                *(float4*)((char*)ets + (size_t)(c >> 4) * 16384 + (size_t)(c & 15) * 1024 + l * 16) = tmp[i];
            }
            if (tid < 128) me2s[tid] = me2g[codebase + tid];
        }
        __syncthreads();

        for (int t = 0; t < 8; ++t) {
            bf16x8 ea[3][2];
#pragma unroll
            for (int lvl = 0; lvl < 3; ++lvl)
#pragma unroll
                for (int kc = 0; kc < 2; ++kc)
                    ea[lvl][kc] = *(const bf16x8*)((const char*)ets + (size_t)lvl * 16384
                                   + (size_t)((kc * 4 + hi4) * 128 + t * 16 + l15) * 16);
            f32x4 me2v = *(const f32x4*)(me2s + t * 16 + hi4 * 4);
            f32x4 acc0 = {0.f, 0.f, 0.f, 0.f};
            f32x4 acc1 = {0.f, 0.f, 0.f, 0.f};
            f32x4 acc2 = {0.f, 0.f, 0.f, 0.f};
            f32x4 acc3 = {0.f, 0.f, 0.f, 0.f};
            // smallest-magnitude products first for fp32-grade accumulation
            PAIR(2, 0) PAIR(1, 1) PAIR(0, 2) PAIR(1, 0) PAIR(0, 1) PAIR(0, 0)

            const int ibase = codebase + t * 16 + hi4 * 4;
#pragma unroll
            for (int r = 0; r < 4; ++r) {
                float sv[4] = {acc0[r] + me2v[r], acc1[r] + me2v[r],
                               acc2[r] + me2v[r], acc3[r] + me2v[r]};
                const int idx = ibase + r;
#pragma unroll
                for (int m = 0; m < 4; ++m) {
                    float s = sv[m];
                    if (s > b1m[m]) { b2m[m] = b1m[m]; b2i[m] = b1i[m]; b1m[m] = s; b1i[m] = idx; }
                    else if (s > b2m[m]) { b2m[m] = s; b2i[m] = idx; }
                }
            }
        }
    }

    // merge the 4 lane-groups (each point lives in lanes l15, +16, +32, +48)
#pragma unroll
    for (int m = 0; m < 4; ++m) {
#pragma unroll
        for (int k = 16; k <= 32; k += 16) {
            float ob1 = __shfl_xor(b1m[m], k); int oi1 = __shfl_xor(b1i[m], k);
            float ob2 = __shfl_xor(b2m[m], k); int oi2 = __shfl_xor(b2i[m], k);
            float nb1, nb2; int ni1, ni2;
            if (ob1 > b1m[m]) {
                nb1 = ob1; ni1 = oi1;
                if (b1m[m] >= ob2) { nb2 = b1m[m]; ni2 = b1i[m]; } else { nb2 = ob2; ni2 = oi2; }
            } else {
                nb1 = b1m[m]; ni1 = b1i[m];
                if (ob1 >= b2m[m]) { nb2 = ob1; ni2 = oi1; } else { nb2 = b2m[m]; ni2 = b2i[m]; }
            }
            b1m[m] = nb1; b1i[m] = ni1; b2m[m] = nb2; b2i[m] = ni2;
        }
    }
    if (l < 16) {
#pragma unroll
        for (int m = 0; m < 4; ++m) {
            pb1i[(size_t)split * NPTS + ptw + m * 16 + l15] = b1i[m];
            pb2i[(size_t)split * NPTS + ptw + m * 16 + l15] = b2i[m];
        }
    }
}

// exact fp32 rescoring of the 8 candidates per point (4 splits x top-2)
__global__ __launch_bounds__(256) void k_refine(
    const float* __restrict__ z, const float* __restrict__ embed,
    const float* __restrict__ me2,
    const int* __restrict__ pb1i, const int* __restrict__ pb2i,
    int* __restrict__ codes_i, float* __restrict__ out_codes)
{
    int n = blockIdx.x * 256 + threadIdx.x;
    int b = n >> 12, hw = n & 4095;
    const float* zp = z + (size_t)b * D * HWSZ + hw;
    float x[64];
#pragma unroll
    for (int c = 0; c < 64; ++c) x[c] = zp[(size_t)c * HWSZ];

    int cand[8];
#pragma unroll
    for (int s = 0; s < KSPLIT; ++s) {
        cand[2 * s]     = pb1i[(size_t)s * NPTS + n];
        cand[2 * s + 1] = pb2i[(size_t)s * NPTS + n];
    }
    float bm = -FLT_MAX; int bi = 0x7fffffff;
#pragma unroll
    for (int j = 0; j < 8; ++j) {
        int ci = cand[j];
        const float4* er = (const float4*)(embed + (size_t)ci * D);
        float dot = 0.f;
#pragma unroll
        for (int q = 0; q < 16; ++q) {
            float4 e4 = er[q];
            dot = fmaf(x[4 * q + 0], e4.x, dot);
            dot = fmaf(x[4 * q + 1], e4.y, dot);
            dot = fmaf(x[4 * q + 2], e4.z, dot);
            dot = fmaf(x[4 * q + 3], e4.w, dot);
        }
        // m = dot - 0.5*e2 ; max-m == min-(e2-2dot) exactly (x2 scaling exact)
        float m = dot + me2[ci];
        if (m > bm || (m == bm && ci < bi)) { bm = m; bi = ci; }
    }
    codes_i[n] = bi;
    out_codes[n] = (float)bi;
}

// z_q gather + segment-sum scatters
__global__ __launch_bounds__(256) void k_gather(
    const float* __restrict__ z, const float* __restrict__ embed,
    const int* __restrict__ codes_i, float* __restrict__ zq,
    float* __restrict__ csb, float* __restrict__ esum)
{
    int n = blockIdx.x * 256 + threadIdx.x;
    int b = n >> 12, hw = n & 4095;
    int code = codes_i[n];
    atomicAdd(&csb[code], 1.0f);
    const float* er = embed + (size_t)code * D;
    size_t zoff = (size_t)b * D * HWSZ + hw;
#pragma unroll 4
    for (int c = 0; c < D; ++c) {
        float xv = z[zoff + (size_t)c * HWSZ];
        zq[zoff + (size_t)c * HWSZ] = er[c];
        atomicAdd(&esum[code * D + c], xv);
    }
}

__global__ void k_cs(const float* __restrict__ cs, const float* __restrict__ csb,
                     float* __restrict__ out_ncs, float* __restrict__ nsum)
{
    int k = blockIdx.x * 256 + threadIdx.x;
    float v = cs[k] * DECAY_F + csb[k] * OMD_F;
    out_ncs[k] = v;
    float t = v;
    t += __shfl_xor(t, 32);
    t += __shfl_xor(t, 16);
    t += __shfl_xor(t, 8);
    t += __shfl_xor(t, 4);
    t += __shfl_xor(t, 2);
    t += __shfl_xor(t, 1);
    if ((threadIdx.x & 63) == 0) atomicAdd(nsum, t);
}

__global__ void k_upd(const float* __restrict__ eavg, const float* __restrict__ esum,
                      const float* __restrict__ ncs, const float* __restrict__ nsum,
                      float* __restrict__ out_nea, float* __restrict__ out_ne)
{
    int k = blockIdx.x * 4 + (threadIdx.x >> 6);
    int lane = threadIdx.x & 63;
    int idx = k * D + lane;
    float ea = eavg[idx] * DECAY_F + esum[idx] * OMD_F;
    out_nea[idx] = ea;
    float n = *nsum;
    float csm = (ncs[k] + EPS_F) / (n + (float)NCODES * EPS_F) * n;
    float v = ea / csm;
    float s = v * v;
    s += __shfl_xor(s, 32);
    s += __shfl_xor(s, 16);
    s += __shfl_xor(s, 8);
    s += __shfl_xor(s, 4);
    s += __shfl_xor(s, 2);
    s += __shfl_xor(s, 1);
    out_ne[idx] = v / sqrtf(s);
}

extern "C" void kernel_launch(void* const* d_in, const int* in_sizes, int n_in,
                              void* d_out, int out_size, void* d_ws, size_t ws_size,
                              hipStream_t stream) {
    const float* z     = (const float*)d_in[0];
    const float* embed = (const float*)d_in[1];
    const float* cs    = (const float*)d_in[2];
    const float* eavg  = (const float*)d_in[3];

    float* out = (float*)d_out;
    float* zq        = out + ZQ_OFF;
    float* out_codes = out + CODES_OFF;
    float* out_ne    = out + NE_OFF;
    float* out_ncs   = out + NCS_OFF;
    float* out_nea   = out + NEA_OFF;

    float* ws = (float*)d_ws;
    float* csb    = ws + WS_CSB;
    float* nsum   = ws + WS_NSUM;
    float* esum   = ws + WS_ESUM;
    int*   codesi = (int*)(ws + WS_CODES);
    int*   pb1i   = (int*)(ws + WS_PB1I);
    int*   pb2i   = (int*)(ws + WS_PB2I);
    float* me2    = ws + WS_ME2;
    unsigned short* eb0 = (unsigned short*)(ws + WS_EB);
    unsigned short* eb1 = (unsigned short*)(ws + WS_EB + 262144);
    unsigned short* eb2 = (unsigned short*)(ws + WS_EB + 524288);
    unsigned short* zb0 = (unsigned short*)(ws + WS_ZB);
    unsigned short* zb1 = (unsigned short*)(ws + WS_ZB + 1048576);
    unsigned short* zb2 = (unsigned short*)(ws + WS_ZB + 2097152);

    // zero csb + nsum + esum (contiguous at offset 0)
    hipMemsetAsync(d_ws, 0, (size_t)(8192 + 64 + 524288) * sizeof(float), stream);

    k_prep_e<<<NCODES / 256, 256, 0, stream>>>(embed, eb0, eb1, eb2, me2);
    k_prep_z<<<NPTS / 256, 256, 0, stream>>>(z, zb0, zb1, zb2);
    k_argmin_mfma<<<128 * KSPLIT, 256, 0, stream>>>(eb0, eb1, eb2, zb0, zb1, zb2, me2, pb1i, pb2i);
    k_refine<<<NPTS / 256, 256, 0, stream>>>(z, embed, me2, pb1i, pb2i, codesi, out_codes);
    k_gather<<<NPTS / 256, 256, 0, stream>>>(z, embed, codesi, zq, csb, esum);
    k_cs<<<NCODES / 256, 256, 0, stream>>>(cs, csb, out_ncs, nsum);
    k_upd<<<NCODES / 4, 256, 0, stream>>>(eavg, esum, out_ncs, nsum, out_nea, out_ne);
}

// Round 5
// 335.481 us; speedup vs baseline: 3.2608x; 1.0237x over previous
//
#include <hip/hip_runtime.h>
#include <math.h>
#include <float.h>

#define NPTS   32768
#define NCODES 8192
#define D      64
#define HWSZ   4096
#define KSPLIT 4
#define NSTAGE 16            // stages per split (64 total / KSPLIT)

#define DECAY_F 0.99f
#define OMD_F   ((float)(1.0 - 0.99))
#define EPS_F   1e-5f

typedef __attribute__((ext_vector_type(8)))  short bf16x8;
typedef __attribute__((ext_vector_type(8)))  unsigned short us8;
typedef __attribute__((ext_vector_type(4)))  float f32x4;
typedef __attribute__((ext_vector_type(16))) float f32x16;

// ---- d_out layout (floats) ----
#define ZQ_OFF    0
#define CODES_OFF 2097152
#define NE_OFF    2129920
#define NCS_OFF   2654208
#define NEA_OFF   2662400

// ---- workspace layout (floats) ----
#define WS_CSB   0         // 8192
#define WS_PSUM  8192      // 64 (32 used)
#define WS_ESUM  8256      // 524288
#define WS_PB1G  532544    // 131072 (int)
#define WS_PB2G  663616    // 131072 (int)
#define WS_ME2   794688    // 8192
#define WS_EB    802880    // 3 planes x 262144 floats (1MB each, ushort data)
#define WS_ZB    1589312   // 3 planes x 1048576 floats (4MB each, ushort data)

__device__ __forceinline__ unsigned short f2bf(float x) {
    unsigned int u = __float_as_uint(x);
    unsigned int r = (u + 0x7fffu + ((u >> 16) & 1u)) >> 16;
    return (unsigned short)r;
}
__device__ __forceinline__ float bf2f(unsigned short b) {
    return __uint_as_float(((unsigned int)b) << 16);
}

// Fused prep: blocks 0..31: embed->3 bf16 planes + me2 + csb=0 + partial sum(cs)
//             blocks 32..159: z->3 bf16 planes + esum=0
__global__ __launch_bounds__(256) void k_prep(
    const float* __restrict__ z, const float* __restrict__ embed,
    const float* __restrict__ cs_in,
    unsigned short* __restrict__ eb0, unsigned short* __restrict__ eb1,
    unsigned short* __restrict__ eb2,
    unsigned short* __restrict__ zb0, unsigned short* __restrict__ zb1,
    unsigned short* __restrict__ zb2,
    float* __restrict__ me2, float* __restrict__ csb,
    float* __restrict__ psum, float* __restrict__ esum)
{
    const int tid = threadIdx.x;
    if (blockIdx.x < 32) {
        int c = blockIdx.x * 256 + tid;
        const float4* src = (const float4*)(embed + (size_t)c * D);
        float row[64];
        float s2 = 0.f;
#pragma unroll
        for (int i = 0; i < 16; ++i) {
            float4 v = src[i];
            row[i * 4 + 0] = v.x; row[i * 4 + 1] = v.y;
            row[i * 4 + 2] = v.z; row[i * 4 + 3] = v.w;
            s2 += v.x * v.x; s2 += v.y * v.y; s2 += v.z * v.z; s2 += v.w * v.w;
        }
        size_t base = (size_t)(c >> 7) * 8192 + (size_t)(c & 127) * 8;
#pragma unroll
        for (int s = 0; s < 8; ++s) {
            us8 v0, v1, v2;
#pragma unroll
            for (int j = 0; j < 8; ++j) {
                float x = row[s * 8 + j];
                unsigned short a = f2bf(x);  float fa = bf2f(a);
                float r1 = x - fa;
                unsigned short b = f2bf(r1); float fb = bf2f(b);
                float r2 = r1 - fb;
                unsigned short cc = f2bf(r2);
                v0[j] = a; v1[j] = b; v2[j] = cc;
            }
            *(us8*)(eb0 + base + (size_t)s * 1024) = v0;
            *(us8*)(eb1 + base + (size_t)s * 1024) = v1;
            *(us8*)(eb2 + base + (size_t)s * 1024) = v2;
        }
        me2[c] = -0.5f * s2;
        csb[c] = 0.f;
        // partial sum of cs over this block -> psum[blk]
        float t = cs_in[c];
        t += __shfl_xor(t, 32); t += __shfl_xor(t, 16); t += __shfl_xor(t, 8);
        t += __shfl_xor(t, 4);  t += __shfl_xor(t, 2);  t += __shfl_xor(t, 1);
        __shared__ float wsum[4];
        if ((tid & 63) == 0) wsum[tid >> 6] = t;
        __syncthreads();
        if (tid == 0) psum[blockIdx.x] = (wsum[0] + wsum[1]) + (wsum[2] + wsum[3]);
    } else {
        int n = (blockIdx.x - 32) * 256 + tid;
        // zero esum slice (16 floats per thread covers 524288)
        f32x4 zz = {0.f, 0.f, 0.f, 0.f};
#pragma unroll
        for (int i = 0; i < 4; ++i) *(f32x4*)(esum + (size_t)n * 16 + i * 4) = zz;
        int b = n >> 12, hw = n & 4095;
        const float* zp = z + (size_t)b * D * HWSZ + hw;
        float row[64];
#pragma unroll
        for (int c = 0; c < 64; ++c) row[c] = zp[(size_t)c * HWSZ];
#pragma unroll
        for (int s = 0; s < 8; ++s) {
            us8 v0, v1, v2;
#pragma unroll
            for (int j = 0; j < 8; ++j) {
                float x = row[s * 8 + j];
                unsigned short a = f2bf(x);  float fa = bf2f(a);
                float r1 = x - fa;
                unsigned short b2 = f2bf(r1); float fb = bf2f(b2);
                float r2 = r1 - fb;
                unsigned short cc = f2bf(r2);
                v0[j] = a; v1[j] = b2; v2[j] = cc;
            }
            *(us8*)(zb0 + (size_t)n * 64 + s * 8) = v0;
            *(us8*)(zb1 + (size_t)n * 64 + s * 8) = v1;
            *(us8*)(zb2 + (size_t)n * 64 + s * 8) = v2;
        }
    }
}

#define MFMA32 __builtin_amdgcn_mfma_f32_32x32x16_bf16
#define P32(a, b, kc) \
    acc0 = MFMA32(ea[a][kc], zf[0][b][kc], acc0, 0, 0, 0); \
    acc1 = MFMA32(ea[a][kc], zf[1][b][kc], acc1, 0, 0, 0);
#define PASS(a, b) P32(a, b, 0) P32(a, b, 1) P32(a, b, 2) P32(a, b, 3)

#define TOP2(nt, g, gi) { \
    bool c1 = (g) > b1m[nt]; \
    bool c2 = (g) > b2m[nt]; \
    b2m[nt] = c1 ? b1m[nt] : (c2 ? (g) : b2m[nt]); \
    b2g[nt] = c1 ? b1g[nt] : (c2 ? (gi) : b2g[nt]); \
    b1m[nt] = c1 ? (g) : b1m[nt]; \
    b1g[nt] = c1 ? (gi) : b1g[nt]; }

#define SCORES(accX, nt) { \
    _Pragma("unroll") \
    for (int q = 0; q < 4; ++q) { \
        float s0 = accX[4 * q + 0] + meq[q][0]; \
        float s1 = accX[4 * q + 1] + meq[q][1]; \
        float s2 = accX[4 * q + 2] + meq[q][2]; \
        float s3 = accX[4 * q + 3] + meq[q][3]; \
        float g = fmaxf(fmaxf(s0, s1), fmaxf(s2, s3)); \
        int gi = gib + q * 2; \
        TOP2(nt, g, gi) \
    } }

// MFMA argmin, 32x32x16: block = 256 pts x 2048 codes (one split).
// Wave = 64 pts (2 N-tiles of 32); A = embed tile from LDS, B = z in regs.
// Tracks top-2 GROUPS of 4 codes (by group-max of m = dot - 0.5*e2) per split.
__global__ __launch_bounds__(256, 2) void k_argmin_mfma(
    const unsigned short* __restrict__ eb0, const unsigned short* __restrict__ eb1,
    const unsigned short* __restrict__ eb2,
    const unsigned short* __restrict__ zb0, const unsigned short* __restrict__ zb1,
    const unsigned short* __restrict__ zb2,
    const float* __restrict__ me2g,
    int* __restrict__ pb1g, int* __restrict__ pb2g)
{
    __shared__ unsigned short ets[3 * 8192];   // 48KB: [lvl][dchunk(8)][ci(128)][8]
    __shared__ float me2s[128];

    const int tid = threadIdx.x;
    const int l = tid & 63;
    const int w = tid >> 6;
    const int l31 = l & 31;
    const int hi = l >> 5;
    const int split = blockIdx.x >> 7;
    const int pgrp  = blockIdx.x & 127;
    const int ptw   = pgrp * 256 + w * 64;

    // B fragments: z for this wave's 64 points (2 tiles of 32), 3 levels, 4 K-chunks
    bf16x8 zf[2][3][4];
#pragma unroll
    for (int nt = 0; nt < 2; ++nt) {
        const size_t roff = (size_t)(ptw + nt * 32 + l31) * 64;
#pragma unroll
        for (int kc = 0; kc < 4; ++kc) {
            zf[nt][0][kc] = *(const bf16x8*)(zb0 + roff + kc * 16 + hi * 8);
            zf[nt][1][kc] = *(const bf16x8*)(zb1 + roff + kc * 16 + hi * 8);
            zf[nt][2][kc] = *(const bf16x8*)(zb2 + roff + kc * 16 + hi * 8);
        }
    }

    float b1m[2] = {-FLT_MAX, -FLT_MAX}, b2m[2] = {-FLT_MAX, -FLT_MAX};
    int   b1g[2] = {0, 0},               b2g[2] = {0, 0};

    for (int stg = 0; stg < NSTAGE; ++stg) {
        const int sg = split * NSTAGE + stg;
        const int codebase = sg * 128;
        __syncthreads();
        {
            const char* s0 = (const char*)eb0 + (size_t)sg * 16384;
            const char* s1 = (const char*)eb1 + (size_t)sg * 16384;
            const char* s2 = (const char*)eb2 + (size_t)sg * 16384;
#pragma unroll
            for (int h = 0; h < 2; ++h) {
                float4 tmp[6];
#pragma unroll
                for (int i = 0; i < 6; ++i) {
                    int c = w * 12 + h * 6 + i;
                    int lvl = c >> 4;
                    const char* sp = (lvl == 0) ? s0 : ((lvl == 1) ? s1 : s2);
                    tmp[i] = *(const float4*)(sp + (size_t)(c & 15) * 1024 + l * 16);
                }
#pragma unroll
                for (int i = 0; i < 6; ++i) {
                    int c = w * 12 + h * 6 + i;
                    *(float4*)((char*)ets + (size_t)(c >> 4) * 16384 + (size_t)(c & 15) * 1024 + l * 16) = tmp[i];
                }
            }
            if (tid < 128) me2s[tid] = me2g[codebase + tid];
        }
        __syncthreads();

#pragma unroll
        for (int ct = 0; ct < 4; ++ct) {
            bf16x8 ea[3][4];
#pragma unroll
            for (int lvl = 0; lvl < 3; ++lvl)
#pragma unroll
                for (int kc = 0; kc < 4; ++kc)
                    ea[lvl][kc] = *(const bf16x8*)((const char*)ets + (size_t)lvl * 16384
                                   + (size_t)(kc * 2 + hi) * 2048 + (size_t)(ct * 32 + l31) * 16);
            f32x4 meq[4];
#pragma unroll
            for (int q = 0; q < 4; ++q)
                meq[q] = *(const f32x4*)(me2s + ct * 32 + q * 8 + hi * 4);

            f32x16 acc0 = {0.f}; f32x16 acc1 = {0.f};
#pragma unroll
            for (int r = 0; r < 16; ++r) { acc0[r] = 0.f; acc1[r] = 0.f; }
            // smallest-magnitude plane products first
            PASS(2, 0) PASS(1, 1) PASS(0, 2) PASS(1, 0) PASS(0, 1) PASS(0, 0)

            const int gib = sg * 32 + ct * 8 + hi;
            SCORES(acc0, 0)
            SCORES(acc1, 1)
        }
    }

    // merge hi halves (points live in lanes l31 and l31+32)
#pragma unroll
    for (int nt = 0; nt < 2; ++nt) {
        float o1 = __shfl_xor(b1m[nt], 32); int o1g = __shfl_xor(b1g[nt], 32);
        float o2 = __shfl_xor(b2m[nt], 32); int o2g = __shfl_xor(b2g[nt], 32);
        float n1m, n2m; int n1g, n2g;
        if (o1 > b1m[nt]) {
            n1m = o1; n1g = o1g;
            if (b1m[nt] >= o2) { n2m = b1m[nt]; n2g = b1g[nt]; } else { n2m = o2; n2g = o2g; }
        } else {
            n1m = b1m[nt]; n1g = b1g[nt];
            if (o1 >= b2m[nt]) { n2m = o1; n2g = o1g; } else { n2m = b2m[nt]; n2g = b2g[nt]; }
        }
        b1m[nt] = n1m; b1g[nt] = n1g; b2m[nt] = n2m; b2g[nt] = n2g;
    }
    if (l < 32) {
#pragma unroll
        for (int nt = 0; nt < 2; ++nt) {
            pb1g[(size_t)split * NPTS + ptw + nt * 32 + l31] = b1g[nt];
            pb2g[(size_t)split * NPTS + ptw + nt * 32 + l31] = b2g[nt];
        }
    }
}

// Exact fp32 rescore of 32 candidates (4 splits x 2 groups x 4 codes),
// then fused z_q gather + segment-sum scatter.
__global__ __launch_bounds__(128) void k_refine_gather(
    const float* __restrict__ z, const float* __restrict__ embed,
    const float* __restrict__ me2,
    const int* __restrict__ pb1g, const int* __restrict__ pb2g,
    float* __restrict__ out_codes, float* __restrict__ zq,
    float* __restrict__ csb, float* __restrict__ esum)
{
    int n = blockIdx.x * 128 + threadIdx.x;
    int b = n >> 12, hw = n & 4095;
    const float* zp = z + (size_t)b * D * HWSZ + hw;
    float x[64];
#pragma unroll
    for (int c = 0; c < 64; ++c) x[c] = zp[(size_t)c * HWSZ];

    int cand[8];
#pragma unroll
    for (int s = 0; s < KSPLIT; ++s) {
        cand[2 * s]     = pb1g[(size_t)s * NPTS + n];
        cand[2 * s + 1] = pb2g[(size_t)s * NPTS + n];
    }
    float bm = -FLT_MAX; int bi = 0x7fffffff;
#pragma unroll 2
    for (int j = 0; j < 8; ++j) {
        const int c0 = cand[j] * 4;
#pragma unroll
        for (int r = 0; r < 4; ++r) {
            const int ci = c0 + r;
            const float4* er = (const float4*)(embed + (size_t)ci * D);
            float dot = 0.f;
#pragma unroll
            for (int q = 0; q < 16; ++q) {
                float4 e4 = er[q];
                dot = fmaf(x[4 * q + 0], e4.x, dot);
                dot = fmaf(x[4 * q + 1], e4.y, dot);
                dot = fmaf(x[4 * q + 2], e4.z, dot);
                dot = fmaf(x[4 * q + 3], e4.w, dot);
            }
            float m = dot + me2[ci];
            if (m > bm || (m == bm && ci < bi)) { bm = m; bi = ci; }
        }
    }
    out_codes[n] = (float)bi;
    atomicAdd(&csb[bi], 1.0f);
    const float* er = embed + (size_t)bi * D;
    size_t zoff = (size_t)b * D * HWSZ + hw;
#pragma unroll 4
    for (int c = 0; c < D; ++c) {
        zq[zoff + (size_t)c * HWSZ] = er[c];
        atomicAdd(&esum[bi * D + c], x[c]);
    }
}

// Fused EMA update + normalize. n computed analytically:
// n = sum(ncs) = DECAY*sum(cs) + OMD*NPTS  (sum(cs_batch) == NPTS exactly)
__global__ void k_cs_upd(const float* __restrict__ cs, const float* __restrict__ csb,
                         const float* __restrict__ eavg, const float* __restrict__ esum,
                         const float* __restrict__ psum,
                         float* __restrict__ out_ncs, float* __restrict__ out_nea,
                         float* __restrict__ out_ne)
{
    int k = blockIdx.x * 4 + (threadIdx.x >> 6);
    int lane = threadIdx.x & 63;
    float S = 0.f;
#pragma unroll
    for (int i = 0; i < 32; ++i) S += psum[i];
    float n = DECAY_F * S + OMD_F * (float)NPTS;

    float v = cs[k] * DECAY_F + csb[k] * OMD_F;
    if (lane == 0) out_ncs[k] = v;

    int idx = k * D + lane;
    float ea = eavg[idx] * DECAY_F + esum[idx] * OMD_F;
    out_nea[idx] = ea;
    float csm = (v + EPS_F) / (n + (float)NCODES * EPS_F) * n;
    float u = ea / csm;
    float s = u * u;
    s += __shfl_xor(s, 32);
    s += __shfl_xor(s, 16);
    s += __shfl_xor(s, 8);
    s += __shfl_xor(s, 4);
    s += __shfl_xor(s, 2);
    s += __shfl_xor(s, 1);
    out_ne[idx] = u / sqrtf(s);
}

extern "C" void kernel_launch(void* const* d_in, const int* in_sizes, int n_in,
                              void* d_out, int out_size, void* d_ws, size_t ws_size,
                              hipStream_t stream) {
    const float* z     = (const float*)d_in[0];
    const float* embed = (const float*)d_in[1];
    const float* cs    = (const float*)d_in[2];
    const float* eavg  = (const float*)d_in[3];

    float* out = (float*)d_out;
    float* zq        = out + ZQ_OFF;
    float* out_codes = out + CODES_OFF;
    float* out_ne    = out + NE_OFF;
    float* out_ncs   = out + NCS_OFF;
    float* out_nea   = out + NEA_OFF;

    float* ws = (float*)d_ws;
    float* csb   = ws + WS_CSB;
    float* psum  = ws + WS_PSUM;
    float* esum  = ws + WS_ESUM;
    int*   pb1g  = (int*)(ws + WS_PB1G);
    int*   pb2g  = (int*)(ws + WS_PB2G);
    float* me2   = ws + WS_ME2;
    unsigned short* eb0 = (unsigned short*)(ws + WS_EB);
    unsigned short* eb1 = (unsigned short*)(ws + WS_EB + 262144);
    unsigned short* eb2 = (unsigned short*)(ws + WS_EB + 524288);
    unsigned short* zb0 = (unsigned short*)(ws + WS_ZB);
    unsigned short* zb1 = (unsigned short*)(ws + WS_ZB + 1048576);
    unsigned short* zb2 = (unsigned short*)(ws + WS_ZB + 2097152);

    k_prep<<<160, 256, 0, stream>>>(z, embed, cs, eb0, eb1, eb2, zb0, zb1, zb2,
                                    me2, csb, psum, esum);
    k_argmin_mfma<<<128 * KSPLIT, 256, 0, stream>>>(eb0, eb1, eb2, zb0, zb1, zb2,
                                                    me2, pb1g, pb2g);
    k_refine_gather<<<NPTS / 128, 128, 0, stream>>>(z, embed, me2, pb1g, pb2g,
                                                    out_codes, zq, csb, esum);
    k_cs_upd<<<NCODES / 4, 256, 0, stream>>>(cs, csb, eavg, esum, psum,
                                             out_ncs, out_nea, out_ne);
}

// Round 6
// 297.491 us; speedup vs baseline: 3.6771x; 1.1277x over previous
//
#include <hip/hip_runtime.h>
#include <math.h>
#include <float.h>

#define NPTS   32768
#define NCODES 8192
#define D      64
#define HWSZ   4096
#define KSPLIT 8
#define NSTAGE 8             // stages per split (64 stage-groups total / KSPLIT)

#define DECAY_F 0.99f
#define OMD_F   ((float)(1.0 - 0.99))
#define EPS_F   1e-5f

typedef __attribute__((ext_vector_type(8)))  short bf16x8;
typedef __attribute__((ext_vector_type(8)))  unsigned short us8;
typedef __attribute__((ext_vector_type(4)))  float f32x4;
typedef __attribute__((ext_vector_type(16))) float f32x16;

// ---- d_out layout (floats) ----
#define ZQ_OFF    0
#define CODES_OFF 2097152
#define NE_OFF    2129920
#define NCS_OFF   2654208
#define NEA_OFF   2662400

// ---- workspace layout (floats) ----
#define WS_CSB   0          // 8192
#define WS_PSUM  8192       // 64 (32 used)
#define WS_ESUM  8256       // 524288
#define WS_PB1G  532544     // 262144 (int)  : top-1 group per split
#define WS_PB2G  794688     // 262144 (int)  : top-2 group per split
#define WS_ME2   1056832    // 8192
#define WS_EB    1065024    // 2 planes x 262144 floats (1MB each, ushort data)

__device__ __forceinline__ unsigned short f2bf(float x) {
    unsigned int u = __float_as_uint(x);
    unsigned int r = (u + 0x7fffu + ((u >> 16) & 1u)) >> 16;
    return (unsigned short)r;
}
__device__ __forceinline__ float bf2f(unsigned short b) {
    return __uint_as_float(((unsigned int)b) << 16);
}

// embed -> 2 bf16 planes (stage-blocked K-major) + me2 + csb=0 + psum
// plane layout: (code c, dim d) -> plane[(c>>7)*8192 + (d>>3)*1024 + (c&127)*8 + (d&7)]
__global__ __launch_bounds__(256) void k_prep_e(
    const float* __restrict__ embed, const float* __restrict__ cs_in,
    unsigned short* __restrict__ eb0, unsigned short* __restrict__ eb1,
    float* __restrict__ me2, float* __restrict__ csb, float* __restrict__ psum)
{
    __shared__ float wsum[4];
    const int tid = threadIdx.x;
    int c = blockIdx.x * 256 + tid;
    const float4* src = (const float4*)(embed + (size_t)c * D);
    float row[64];
    float s2 = 0.f;
#pragma unroll
    for (int i = 0; i < 16; ++i) {
        float4 v = src[i];
        row[i * 4 + 0] = v.x; row[i * 4 + 1] = v.y;
        row[i * 4 + 2] = v.z; row[i * 4 + 3] = v.w;
        s2 += v.x * v.x; s2 += v.y * v.y; s2 += v.z * v.z; s2 += v.w * v.w;
    }
    size_t base = (size_t)(c >> 7) * 8192 + (size_t)(c & 127) * 8;
#pragma unroll
    for (int s = 0; s < 8; ++s) {
        us8 v0, v1;
#pragma unroll
        for (int j = 0; j < 8; ++j) {
            float x = row[s * 8 + j];
            unsigned short a = f2bf(x);
            float r1 = x - bf2f(a);
            v0[j] = a; v1[j] = f2bf(r1);
        }
        *(us8*)(eb0 + base + (size_t)s * 1024) = v0;
        *(us8*)(eb1 + base + (size_t)s * 1024) = v1;
    }
    me2[c] = -0.5f * s2;
    csb[c] = 0.f;
    float t = cs_in[c];
    t += __shfl_xor(t, 32); t += __shfl_xor(t, 16); t += __shfl_xor(t, 8);
    t += __shfl_xor(t, 4);  t += __shfl_xor(t, 2);  t += __shfl_xor(t, 1);
    if ((tid & 63) == 0) wsum[tid >> 6] = t;
    __syncthreads();
    if (tid == 0) psum[blockIdx.x] = (wsum[0] + wsum[1]) + (wsum[2] + wsum[3]);
}

#define MFMA32 __builtin_amdgcn_mfma_f32_32x32x16_bf16
#define P32(ep, zp, kc) \
    acc0 = MFMA32(ea[ep][kc], (bf16x8)zf[0][zp][kc], acc0, 0, 0, 0); \
    acc1 = MFMA32(ea[ep][kc], (bf16x8)zf[1][zp][kc], acc1, 0, 0, 0);
#define PASS(ep, zp) P32(ep, zp, 0) P32(ep, zp, 1) P32(ep, zp, 2) P32(ep, zp, 3)

#define TOP2(nt, g, gi) { \
    bool c1 = (g) > b1m[nt]; \
    bool c2 = (g) > b2m[nt]; \
    b2m[nt] = c1 ? b1m[nt] : (c2 ? (g) : b2m[nt]); \
    b2g[nt] = c1 ? b1g[nt] : (c2 ? (gi) : b2g[nt]); \
    b1m[nt] = c1 ? (g) : b1m[nt]; \
    b1g[nt] = c1 ? (gi) : b1g[nt]; }

#define SCORES(accX, nt) { \
    _Pragma("unroll") \
    for (int q = 0; q < 4; ++q) { \
        float g = fmaxf(fmaxf(accX[4 * q + 0], accX[4 * q + 1]), \
                        fmaxf(accX[4 * q + 2], accX[4 * q + 3])); \
        TOP2(nt, g, gib + q * 2) \
    } }

// MFMA argmin, 32x32x16, 2-plane bf16, 3 passes (00, 01, 10).
// Block = 256 pts x 1024 codes (one split). Wave = 64 pts (2 N-tiles of 32).
// z is loaded fp32 and plane-split in-register (no z-plane prep pass).
// acc initialized with me2 so final acc IS the score m = dot - 0.5*e2.
__global__ __launch_bounds__(256, 3) void k_argmin_mfma(
    const float* __restrict__ z,
    const unsigned short* __restrict__ eb0, const unsigned short* __restrict__ eb1,
    const float* __restrict__ me2g,
    int* __restrict__ pb1g, int* __restrict__ pb2g)
{
    __shared__ unsigned short ets[2 * 8192];   // 32KB: [lvl][dchunk(8)][ci(128)][8]
    __shared__ float me2s[128];

    const int tid = threadIdx.x;
    const int l = tid & 63;
    const int w = tid >> 6;
    const int l31 = l & 31;
    const int hi = l >> 5;
    const int split = blockIdx.x >> 7;
    const int pgrp  = blockIdx.x & 127;
    const int n0    = pgrp * 256;
    const int b     = n0 >> 12;
    const int hw0   = n0 & 4095;
    const int ptw   = n0 + w * 64;

    // B fragments: z for this wave's 64 points (2 tiles of 32), 2 planes, 4 K-chunks
    const float* zb = z + (size_t)b * D * HWSZ;
    us8 zf[2][2][4];
#pragma unroll
    for (int nt = 0; nt < 2; ++nt) {
        const int hwp = hw0 + w * 64 + nt * 32 + l31;
#pragma unroll
        for (int kc = 0; kc < 4; ++kc) {
            us8 p0, p1;
#pragma unroll
            for (int j = 0; j < 8; ++j) {
                float x = zb[(size_t)(kc * 16 + hi * 8 + j) * HWSZ + hwp];
                unsigned short a = f2bf(x);
                float r = x - bf2f(a);
                p0[j] = a; p1[j] = f2bf(r);
            }
            zf[nt][0][kc] = p0; zf[nt][1][kc] = p1;
        }
    }

    float b1m[2] = {-FLT_MAX, -FLT_MAX}, b2m[2] = {-FLT_MAX, -FLT_MAX};
    int   b1g[2] = {0, 0},               b2g[2] = {0, 0};

    for (int stg = 0; stg < NSTAGE; ++stg) {
        const int sg = split * NSTAGE + stg;
        const int codebase = sg * 128;
        __syncthreads();
        {
            // stage 2 planes x 16KB; linear copy (2048 float4 / 256 thr = 8 each)
            const char* s0 = (const char*)eb0 + (size_t)sg * 16384;
            const char* s1 = (const char*)eb1 + (size_t)sg * 16384;
            float4 tmp[8];
#pragma unroll
            for (int i = 0; i < 8; ++i) {
                int flat = i * 256 + tid;
                const char* sp = (flat < 1024) ? s0 : s1;
                tmp[i] = *(const float4*)(sp + (size_t)(flat & 1023) * 16);
            }
#pragma unroll
            for (int i = 0; i < 8; ++i) {
                int flat = i * 256 + tid;
                *(float4*)((char*)ets + (size_t)flat * 16) = tmp[i];
            }
            if (tid < 128) me2s[tid] = me2g[codebase + tid];
        }
        __syncthreads();

#pragma unroll
        for (int ct = 0; ct < 4; ++ct) {
            bf16x8 ea[2][4];
#pragma unroll
            for (int lvl = 0; lvl < 2; ++lvl)
#pragma unroll
                for (int kc = 0; kc < 4; ++kc)
                    ea[lvl][kc] = *(const bf16x8*)((const char*)ets + (size_t)lvl * 16384
                                   + (size_t)(kc * 2 + hi) * 2048 + (size_t)(ct * 32 + l31) * 16);
            f32x4 meq[4];
#pragma unroll
            for (int q = 0; q < 4; ++q)
                meq[q] = *(const f32x4*)(me2s + ct * 32 + q * 8 + hi * 4);

            f32x16 acc0, acc1;
#pragma unroll
            for (int q = 0; q < 4; ++q)
#pragma unroll
                for (int r = 0; r < 4; ++r) {
                    acc0[q * 4 + r] = meq[q][r];
                    acc1[q * 4 + r] = meq[q][r];
                }
            // cross terms (small) first, then main
            PASS(1, 0) PASS(0, 1) PASS(0, 0)

            const int gib = sg * 32 + ct * 8 + hi;
            SCORES(acc0, 0)
            SCORES(acc1, 1)
        }
    }

    // merge hi halves (points live in lanes l31 and l31+32)
#pragma unroll
    for (int nt = 0; nt < 2; ++nt) {
        float o1 = __shfl_xor(b1m[nt], 32); int o1g = __shfl_xor(b1g[nt], 32);
        float o2 = __shfl_xor(b2m[nt], 32); int o2g = __shfl_xor(b2g[nt], 32);
        float n1m, n2m; int n1g, n2g;
        if (o1 > b1m[nt]) {
            n1m = o1; n1g = o1g;
            if (b1m[nt] >= o2) { n2m = b1m[nt]; n2g = b1g[nt]; } else { n2m = o2; n2g = o2g; }
        } else {
            n1m = b1m[nt]; n1g = b1g[nt];
            if (o1 >= b2m[nt]) { n2m = o1; n2g = o1g; } else { n2m = b2m[nt]; n2g = b2g[nt]; }
        }
        b1m[nt] = n1m; b1g[nt] = n1g; b2m[nt] = n2m; b2g[nt] = n2g;
    }
    if (l < 32) {
#pragma unroll
        for (int nt = 0; nt < 2; ++nt) {
            pb1g[(size_t)split * NPTS + ptw + nt * 32 + l31] = b1g[nt];
            pb2g[(size_t)split * NPTS + ptw + nt * 32 + l31] = b2g[nt];
        }
    }
}

// Exact fp32 rescore of 64 candidates (8 splits x top-2 groups x 4 codes).
// 2 threads per point (half = tid&1 handles 4 splits); partner combine via shfl;
// scatter duties split: half 0 -> zq + csb + codes, half 1 -> esum atomics.
__global__ __launch_bounds__(256) void k_refine_gather(
    const float* __restrict__ z, const float* __restrict__ embed,
    const float* __restrict__ me2,
    const int* __restrict__ pb1g, const int* __restrict__ pb2g,
    float* __restrict__ out_codes, float* __restrict__ zq,
    float* __restrict__ csb, float* __restrict__ esum)
{
    int t = blockIdx.x * 256 + threadIdx.x;
    int n = t >> 1, half = t & 1;
    int b = n >> 12, hw = n & 4095;
    const float* zp = z + (size_t)b * D * HWSZ + hw;
    float x[64];
#pragma unroll
    for (int c = 0; c < 64; ++c) x[c] = zp[(size_t)c * HWSZ];

    int cand[8];
#pragma unroll
    for (int s = 0; s < 4; ++s) {
        int ss = half * 4 + s;
        cand[2 * s]     = pb1g[(size_t)ss * NPTS + n];
        cand[2 * s + 1] = pb2g[(size_t)ss * NPTS + n];
    }
    float bm = -FLT_MAX; int bi = 0x7fffffff;
#pragma unroll 2
    for (int j = 0; j < 8; ++j) {
        const int c0 = cand[j] * 4;
#pragma unroll
        for (int r = 0; r < 4; ++r) {
            const int ci = c0 + r;
            const float4* er = (const float4*)(embed + (size_t)ci * D);
            float dot = 0.f;
#pragma unroll
            for (int q = 0; q < 16; ++q) {
                float4 e4 = er[q];
                dot = fmaf(x[4 * q + 0], e4.x, dot);
                dot = fmaf(x[4 * q + 1], e4.y, dot);
                dot = fmaf(x[4 * q + 2], e4.z, dot);
                dot = fmaf(x[4 * q + 3], e4.w, dot);
            }
            float m = dot + me2[ci];
            if (m > bm || (m == bm && ci < bi)) { bm = m; bi = ci; }
        }
    }
    // combine the two halves of this point
    float om = __shfl_xor(bm, 1); int oi = __shfl_xor(bi, 1);
    if (om > bm || (om == bm && oi < bi)) { bm = om; bi = oi; }

    size_t zoff = (size_t)b * D * HWSZ + hw;
    if (half == 0) {
        out_codes[n] = (float)bi;
        atomicAdd(&csb[bi], 1.0f);
        const float* er = embed + (size_t)bi * D;
#pragma unroll 8
        for (int c = 0; c < D; ++c) zq[zoff + (size_t)c * HWSZ] = er[c];
    } else {
#pragma unroll 8
        for (int c = 0; c < D; ++c) atomicAdd(&esum[bi * D + c], x[c]);
    }
}

// Fused EMA update + normalize. n computed analytically:
// n = sum(ncs) = DECAY*sum(cs) + OMD*NPTS  (sum(cs_batch) == NPTS exactly)
__global__ void k_cs_upd(const float* __restrict__ cs, const float* __restrict__ csb,
                         const float* __restrict__ eavg, const float* __restrict__ esum,
                         const float* __restrict__ psum,
                         float* __restrict__ out_ncs, float* __restrict__ out_nea,
                         float* __restrict__ out_ne)
{
    int k = blockIdx.x * 4 + (threadIdx.x >> 6);
    int lane = threadIdx.x & 63;
    float S = 0.f;
#pragma unroll
    for (int i = 0; i < 32; ++i) S += psum[i];
    float n = DECAY_F * S + OMD_F * (float)NPTS;

    float v = cs[k] * DECAY_F + csb[k] * OMD_F;
    if (lane == 0) out_ncs[k] = v;

    int idx = k * D + lane;
    float ea = eavg[idx] * DECAY_F + esum[idx] * OMD_F;
    out_nea[idx] = ea;
    float csm = (v + EPS_F) / (n + (float)NCODES * EPS_F) * n;
    float u = ea / csm;
    float s = u * u;
    s += __shfl_xor(s, 32);
    s += __shfl_xor(s, 16);
    s += __shfl_xor(s, 8);
    s += __shfl_xor(s, 4);
    s += __shfl_xor(s, 2);
    s += __shfl_xor(s, 1);
    out_ne[idx] = u / sqrtf(s);
}

extern "C" void kernel_launch(void* const* d_in, const int* in_sizes, int n_in,
                              void* d_out, int out_size, void* d_ws, size_t ws_size,
                              hipStream_t stream) {
    const float* z     = (const float*)d_in[0];
    const float* embed = (const float*)d_in[1];
    const float* cs    = (const float*)d_in[2];
    const float* eavg  = (const float*)d_in[3];

    float* out = (float*)d_out;
    float* zq        = out + ZQ_OFF;
    float* out_codes = out + CODES_OFF;
    float* out_ne    = out + NE_OFF;
    float* out_ncs   = out + NCS_OFF;
    float* out_nea   = out + NEA_OFF;

    float* ws = (float*)d_ws;
    float* csb   = ws + WS_CSB;
    float* psum  = ws + WS_PSUM;
    float* esum  = ws + WS_ESUM;
    int*   pb1g  = (int*)(ws + WS_PB1G);
    int*   pb2g  = (int*)(ws + WS_PB2G);
    float* me2   = ws + WS_ME2;
    unsigned short* eb0 = (unsigned short*)(ws + WS_EB);
    unsigned short* eb1 = (unsigned short*)(ws + WS_EB + 262144);

    // zero esum only (csb zeroed in k_prep_e)
    hipMemsetAsync((char*)d_ws + (size_t)WS_ESUM * sizeof(float), 0,
                   (size_t)524288 * sizeof(float), stream);

    k_prep_e<<<NCODES / 256, 256, 0, stream>>>(embed, cs, eb0, eb1, me2, csb, psum);
    k_argmin_mfma<<<128 * KSPLIT, 256, 0, stream>>>(z, eb0, eb1, me2, pb1g, pb2g);
    k_refine_gather<<<NPTS * 2 / 256, 256, 0, stream>>>(z, embed, me2, pb1g, pb2g,
                                                        out_codes, zq, csb, esum);
    k_cs_upd<<<NCODES / 4, 256, 0, stream>>>(cs, csb, eavg, esum, psum,
                                             out_ncs, out_nea, out_ne);
}

// Round 7
// 215.074 us; speedup vs baseline: 5.0863x; 1.3832x over previous
//
#include <hip/hip_runtime.h>
#include <math.h>
#include <float.h>

#define NPTS   32768
#define NCODES 8192
#define D      64
#define HWSZ   4096
#define KSPLIT 8
#define NSTAGE 8             // stages per split (64 stage-groups total / KSPLIT)

#define DECAY_F 0.99f
#define OMD_F   ((float)(1.0 - 0.99))
#define EPS_F   1e-5f

typedef __attribute__((ext_vector_type(8)))  short bf16x8;
typedef __attribute__((ext_vector_type(8)))  unsigned short us8;
typedef __attribute__((ext_vector_type(4)))  float f32x4;
typedef __attribute__((ext_vector_type(16))) float f32x16;

// ---- d_out layout (floats) ----
#define ZQ_OFF    0
#define CODES_OFF 2097152
#define NE_OFF    2129920
#define NCS_OFF   2654208
#define NEA_OFF   2662400

// ---- workspace layout (floats) ----
#define WS_PSUM   0         // 64 (32 used)
#define WS_ME2    64        // 8192
#define WS_HIST   8256      // 8192 (int)
#define WS_BOFF   16448     // 8192 (int)
#define WS_BOFF2  24640     // 8192 (int)
#define WS_CODES  32832     // 32768 (int)
#define WS_ORDER  65600     // 32768 (int)
#define WS_PB1G   98368     // 262144 (int)
#define WS_PB2G   360512    // 262144 (int)
#define WS_EB     622656    // 2 planes x 262144 floats (1MB each, ushort data)
#define WS_ZROW   1146944   // 2097152 : z in [pt][dim] layout for segmented sum

__device__ __forceinline__ unsigned short f2bf(float x) {
    unsigned int u = __float_as_uint(x);
    unsigned int r = (u + 0x7fffu + ((u >> 16) & 1u)) >> 16;
    return (unsigned short)r;
}
__device__ __forceinline__ float bf2f(unsigned short b) {
    return __uint_as_float(((unsigned int)b) << 16);
}

// embed -> 2 bf16 planes (stage-blocked K-major) + me2 + hist=0 + psum
__global__ __launch_bounds__(256) void k_prep_e(
    const float* __restrict__ embed, const float* __restrict__ cs_in,
    unsigned short* __restrict__ eb0, unsigned short* __restrict__ eb1,
    float* __restrict__ me2, int* __restrict__ hist, float* __restrict__ psum)
{
    __shared__ float wsum[4];
    const int tid = threadIdx.x;
    int c = blockIdx.x * 256 + tid;
    const float4* src = (const float4*)(embed + (size_t)c * D);
    float row[64];
    float s2 = 0.f;
#pragma unroll
    for (int i = 0; i < 16; ++i) {
        float4 v = src[i];
        row[i * 4 + 0] = v.x; row[i * 4 + 1] = v.y;
        row[i * 4 + 2] = v.z; row[i * 4 + 3] = v.w;
        s2 += v.x * v.x; s2 += v.y * v.y; s2 += v.z * v.z; s2 += v.w * v.w;
    }
    size_t base = (size_t)(c >> 7) * 8192 + (size_t)(c & 127) * 8;
#pragma unroll
    for (int s = 0; s < 8; ++s) {
        us8 v0, v1;
#pragma unroll
        for (int j = 0; j < 8; ++j) {
            float x = row[s * 8 + j];
            unsigned short a = f2bf(x);
            float r1 = x - bf2f(a);
            v0[j] = a; v1[j] = f2bf(r1);
        }
        *(us8*)(eb0 + base + (size_t)s * 1024) = v0;
        *(us8*)(eb1 + base + (size_t)s * 1024) = v1;
    }
    me2[c] = -0.5f * s2;
    hist[c] = 0;
    float t = cs_in[c];
    t += __shfl_xor(t, 32); t += __shfl_xor(t, 16); t += __shfl_xor(t, 8);
    t += __shfl_xor(t, 4);  t += __shfl_xor(t, 2);  t += __shfl_xor(t, 1);
    if ((tid & 63) == 0) wsum[tid >> 6] = t;
    __syncthreads();
    if (tid == 0) psum[blockIdx.x] = (wsum[0] + wsum[1]) + (wsum[2] + wsum[3]);
}

#define MFMA32 __builtin_amdgcn_mfma_f32_32x32x16_bf16
#define P32(ep, zp, kc) \
    acc0 = MFMA32(ea[ep][kc], (bf16x8)zf[0][zp][kc], acc0, 0, 0, 0); \
    acc1 = MFMA32(ea[ep][kc], (bf16x8)zf[1][zp][kc], acc1, 0, 0, 0);
#define PASS(ep, zp) P32(ep, zp, 0) P32(ep, zp, 1) P32(ep, zp, 2) P32(ep, zp, 3)

#define TOP2(nt, g, gi) { \
    bool c1 = (g) > b1m[nt]; \
    bool c2 = (g) > b2m[nt]; \
    b2m[nt] = c1 ? b1m[nt] : (c2 ? (g) : b2m[nt]); \
    b2g[nt] = c1 ? b1g[nt] : (c2 ? (gi) : b2g[nt]); \
    b1m[nt] = c1 ? (g) : b1m[nt]; \
    b1g[nt] = c1 ? (gi) : b1g[nt]; }

#define SCORES(accX, nt) { \
    _Pragma("unroll") \
    for (int q = 0; q < 4; ++q) { \
        float g = fmaxf(fmaxf(accX[4 * q + 0], accX[4 * q + 1]), \
                        fmaxf(accX[4 * q + 2], accX[4 * q + 3])); \
        TOP2(nt, g, gib + q * 2) \
    } }

// MFMA argmin, 32x32x16, 2-plane bf16, 3 passes (00, 01, 10).
// Block = 256 pts x 1024 codes (one split). Wave = 64 pts (2 N-tiles of 32).
__global__ __launch_bounds__(256, 3) void k_argmin_mfma(
    const float* __restrict__ z,
    const unsigned short* __restrict__ eb0, const unsigned short* __restrict__ eb1,
    const float* __restrict__ me2g,
    int* __restrict__ pb1g, int* __restrict__ pb2g)
{
    __shared__ unsigned short ets[2 * 8192];   // 32KB
    __shared__ float me2s[128];

    const int tid = threadIdx.x;
    const int l = tid & 63;
    const int w = tid >> 6;
    const int l31 = l & 31;
    const int hi = l >> 5;
    const int split = blockIdx.x >> 7;
    const int pgrp  = blockIdx.x & 127;
    const int n0    = pgrp * 256;
    const int b     = n0 >> 12;
    const int hw0   = n0 & 4095;
    const int ptw   = n0 + w * 64;

    const float* zb = z + (size_t)b * D * HWSZ;
    us8 zf[2][2][4];
#pragma unroll
    for (int nt = 0; nt < 2; ++nt) {
        const int hwp = hw0 + w * 64 + nt * 32 + l31;
#pragma unroll
        for (int kc = 0; kc < 4; ++kc) {
            us8 p0, p1;
#pragma unroll
            for (int j = 0; j < 8; ++j) {
                float x = zb[(size_t)(kc * 16 + hi * 8 + j) * HWSZ + hwp];
                unsigned short a = f2bf(x);
                float r = x - bf2f(a);
                p0[j] = a; p1[j] = f2bf(r);
            }
            zf[nt][0][kc] = p0; zf[nt][1][kc] = p1;
        }
    }

    float b1m[2] = {-FLT_MAX, -FLT_MAX}, b2m[2] = {-FLT_MAX, -FLT_MAX};
    int   b1g[2] = {0, 0},               b2g[2] = {0, 0};

    for (int stg = 0; stg < NSTAGE; ++stg) {
        const int sg = split * NSTAGE + stg;
        const int codebase = sg * 128;
        __syncthreads();
        {
            const char* s0 = (const char*)eb0 + (size_t)sg * 16384;
            const char* s1 = (const char*)eb1 + (size_t)sg * 16384;
            float4 tmp[8];
#pragma unroll
            for (int i = 0; i < 8; ++i) {
                int flat = i * 256 + tid;
                const char* sp = (flat < 1024) ? s0 : s1;
                tmp[i] = *(const float4*)(sp + (size_t)(flat & 1023) * 16);
            }
#pragma unroll
            for (int i = 0; i < 8; ++i) {
                int flat = i * 256 + tid;
                *(float4*)((char*)ets + (size_t)flat * 16) = tmp[i];
            }
            if (tid < 128) me2s[tid] = me2g[codebase + tid];
        }
        __syncthreads();

#pragma unroll
        for (int ct = 0; ct < 4; ++ct) {
            bf16x8 ea[2][4];
#pragma unroll
            for (int lvl = 0; lvl < 2; ++lvl)
#pragma unroll
                for (int kc = 0; kc < 4; ++kc)
                    ea[lvl][kc] = *(const bf16x8*)((const char*)ets + (size_t)lvl * 16384
                                   + (size_t)(kc * 2 + hi) * 2048 + (size_t)(ct * 32 + l31) * 16);
            f32x4 meq[4];
#pragma unroll
            for (int q = 0; q < 4; ++q)
                meq[q] = *(const f32x4*)(me2s + ct * 32 + q * 8 + hi * 4);

            f32x16 acc0, acc1;
#pragma unroll
            for (int q = 0; q < 4; ++q)
#pragma unroll
                for (int r = 0; r < 4; ++r) {
                    acc0[q * 4 + r] = meq[q][r];
                    acc1[q * 4 + r] = meq[q][r];
                }
            PASS(1, 0) PASS(0, 1) PASS(0, 0)

            const int gib = sg * 32 + ct * 8 + hi;
            SCORES(acc0, 0)
            SCORES(acc1, 1)
        }
    }

#pragma unroll
    for (int nt = 0; nt < 2; ++nt) {
        float o1 = __shfl_xor(b1m[nt], 32); int o1g = __shfl_xor(b1g[nt], 32);
        float o2 = __shfl_xor(b2m[nt], 32); int o2g = __shfl_xor(b2g[nt], 32);
        float n1m, n2m; int n1g, n2g;
        if (o1 > b1m[nt]) {
            n1m = o1; n1g = o1g;
            if (b1m[nt] >= o2) { n2m = b1m[nt]; n2g = b1g[nt]; } else { n2m = o2; n2g = o2g; }
        } else {
            n1m = b1m[nt]; n1g = b1g[nt];
            if (o1 >= b2m[nt]) { n2m = o1; n2g = o1g; } else { n2m = b2m[nt]; n2g = b2g[nt]; }
        }
        b1m[nt] = n1m; b1g[nt] = n1g; b2m[nt] = n2m; b2g[nt] = n2g;
    }
    if (l < 32) {
#pragma unroll
        for (int nt = 0; nt < 2; ++nt) {
            pb1g[(size_t)split * NPTS + ptw + nt * 32 + l31] = b1g[nt];
            pb2g[(size_t)split * NPTS + ptw + nt * 32 + l31] = b2g[nt];
        }
    }
}

// Exact fp32 rescore: block = 32 points, 8 threads/point (one per split).
// Subtask 0 writes codes/zq/hist; all subtasks write zrow (8 dims each).
__global__ __launch_bounds__(256) void k_refine(
    const float* __restrict__ z, const float* __restrict__ embed,
    const float* __restrict__ me2,
    const int* __restrict__ pb1g, const int* __restrict__ pb2g,
    int* __restrict__ codes_i, float* __restrict__ out_codes,
    float* __restrict__ zq, int* __restrict__ hist, float* __restrict__ zrow)
{
    __shared__ float xs[64 * 32];    // [c][pi]
    __shared__ float sbm[256];
    __shared__ int   sbi[256];
    const int tid = threadIdx.x;
    const int pi = tid & 31, s = tid >> 5;
    const int n0 = blockIdx.x * 32;
    const int b = n0 >> 12, hw0 = n0 & 4095;
    const int n = n0 + pi;

    const float* zb = z + (size_t)b * D * HWSZ + hw0;
#pragma unroll
    for (int i = 0; i < 8; ++i) {
        int c = s * 8 + i;
        xs[c * 32 + pi] = zb[(size_t)c * HWSZ + pi];
    }
    __syncthreads();
    float x[64];
#pragma unroll
    for (int c = 0; c < 64; ++c) x[c] = xs[c * 32 + pi];

    int cand[2];
    cand[0] = pb1g[(size_t)s * NPTS + n];
    cand[1] = pb2g[(size_t)s * NPTS + n];
    float bm = -FLT_MAX; int bi = 0x7fffffff;
#pragma unroll
    for (int j = 0; j < 2; ++j) {
        const int c0 = cand[j] * 4;
#pragma unroll
        for (int r = 0; r < 4; ++r) {
            const int ci = c0 + r;
            const float4* er = (const float4*)(embed + (size_t)ci * D);
            float d0 = 0.f, d1 = 0.f, d2 = 0.f, d3 = 0.f;
#pragma unroll
            for (int q = 0; q < 16; ++q) {
                float4 e4 = er[q];
                d0 = fmaf(x[4 * q + 0], e4.x, d0);
                d1 = fmaf(x[4 * q + 1], e4.y, d1);
                d2 = fmaf(x[4 * q + 2], e4.z, d2);
                d3 = fmaf(x[4 * q + 3], e4.w, d3);
            }
            float m = ((d0 + d1) + (d2 + d3)) + me2[ci];
            if (m > bm || (m == bm && ci < bi)) { bm = m; bi = ci; }
        }
    }
    sbm[tid] = bm; sbi[tid] = bi;
    __syncthreads();

    if (s == 0) {
        float B = sbm[pi]; int I = sbi[pi];
#pragma unroll
        for (int t = 1; t < 8; ++t) {
            float m = sbm[t * 32 + pi]; int i2 = sbi[t * 32 + pi];
            if (m > B || (m == B && i2 < I)) { B = m; I = i2; }
        }
        codes_i[n] = I;
        out_codes[n] = (float)I;
        atomicAdd(&hist[I], 1);
        const float* er = embed + (size_t)I * D;
        size_t zoff = (size_t)b * D * HWSZ + hw0 + pi;
#pragma unroll 8
        for (int c = 0; c < 64; ++c) zq[zoff + (size_t)c * HWSZ] = er[c];
    }
    // zrow[n][64]: subtask s writes dims [8s, 8s+8) -> 64B-granular per wave
    {
        float4 a = {x[s * 8 + 0], x[s * 8 + 1], x[s * 8 + 2], x[s * 8 + 3]};
        float4 b4 = {x[s * 8 + 4], x[s * 8 + 5], x[s * 8 + 6], x[s * 8 + 7]};
        *(float4*)(zrow + (size_t)n * 64 + s * 8) = a;
        *(float4*)(zrow + (size_t)n * 64 + s * 8 + 4) = b4;
    }
}

// exclusive prefix sum of hist (8192 ints) -> binoff and binoff2
__global__ __launch_bounds__(1024) void k_scan(
    const int* __restrict__ hist, int* __restrict__ binoff, int* __restrict__ binoff2)
{
    __shared__ int wtot[16];
    __shared__ int wbase[16];
    const int tid = threadIdx.x;
    const int lane = tid & 63, w = tid >> 6;
    int v[8]; int s = 0;
#pragma unroll
    for (int i = 0; i < 8; ++i) { v[i] = hist[tid * 8 + i]; s += v[i]; }
    int inc = s;
#pragma unroll
    for (int off = 1; off < 64; off <<= 1) {
        int t = __shfl_up(inc, off);
        if (lane >= off) inc += t;
    }
    if (lane == 63) wtot[w] = inc;
    __syncthreads();
    if (tid == 0) {
        int a = 0;
#pragma unroll
        for (int i = 0; i < 16; ++i) { int t = wtot[i]; wbase[i] = a; a += t; }
    }
    __syncthreads();
    int excl = wbase[w] + (inc - s);
#pragma unroll
    for (int i = 0; i < 8; ++i) {
        binoff[tid * 8 + i] = excl;
        binoff2[tid * 8 + i] = excl;
        excl += v[i];
    }
}

// scatter point ids into code-sorted order
__global__ void k_reorder(const int* __restrict__ codes_i,
                          int* __restrict__ binoff2, int* __restrict__ order)
{
    int n = blockIdx.x * 256 + threadIdx.x;
    int c = codes_i[n];
    int r = atomicAdd(&binoff2[c], 1);
    order[r] = n;
}

// one wave per code: segmented sum over zrow + fused EMA update + normalize
__global__ __launch_bounds__(256) void k_accum(
    const int* __restrict__ hist, const int* __restrict__ binoff,
    const int* __restrict__ order, const float* __restrict__ zrow,
    const float* __restrict__ cs, const float* __restrict__ eavg,
    const float* __restrict__ psum,
    float* __restrict__ out_ncs, float* __restrict__ out_nea, float* __restrict__ out_ne)
{
    int k = blockIdx.x * 4 + (threadIdx.x >> 6);
    int lane = threadIdx.x & 63;
    int cnt = hist[k], base = binoff[k];
    float acc = 0.f;
    for (int i = 0; i < cnt; ++i) {
        int p = order[base + i];
        acc += zrow[(size_t)p * 64 + lane];
    }
    float S = 0.f;
#pragma unroll
    for (int i = 0; i < 32; ++i) S += psum[i];
    float n = DECAY_F * S + OMD_F * (float)NPTS;

    float v = cs[k] * DECAY_F + (float)cnt * OMD_F;
    if (lane == 0) out_ncs[k] = v;

    int idx = k * D + lane;
    float ea = eavg[idx] * DECAY_F + acc * OMD_F;
    out_nea[idx] = ea;
    float csm = (v + EPS_F) / (n + (float)NCODES * EPS_F) * n;
    float u = ea / csm;
    float ss = u * u;
    ss += __shfl_xor(ss, 32);
    ss += __shfl_xor(ss, 16);
    ss += __shfl_xor(ss, 8);
    ss += __shfl_xor(ss, 4);
    ss += __shfl_xor(ss, 2);
    ss += __shfl_xor(ss, 1);
    out_ne[idx] = u / sqrtf(ss);
}

extern "C" void kernel_launch(void* const* d_in, const int* in_sizes, int n_in,
                              void* d_out, int out_size, void* d_ws, size_t ws_size,
                              hipStream_t stream) {
    const float* z     = (const float*)d_in[0];
    const float* embed = (const float*)d_in[1];
    const float* cs    = (const float*)d_in[2];
    const float* eavg  = (const float*)d_in[3];

    float* out = (float*)d_out;
    float* zq        = out + ZQ_OFF;
    float* out_codes = out + CODES_OFF;
    float* out_ne    = out + NE_OFF;
    float* out_ncs   = out + NCS_OFF;
    float* out_nea   = out + NEA_OFF;

    float* ws = (float*)d_ws;
    float* psum   = ws + WS_PSUM;
    float* me2    = ws + WS_ME2;
    int*   hist   = (int*)(ws + WS_HIST);
    int*   boff   = (int*)(ws + WS_BOFF);
    int*   boff2  = (int*)(ws + WS_BOFF2);
    int*   codesi = (int*)(ws + WS_CODES);
    int*   order  = (int*)(ws + WS_ORDER);
    int*   pb1g   = (int*)(ws + WS_PB1G);
    int*   pb2g   = (int*)(ws + WS_PB2G);
    float* zrow   = ws + WS_ZROW;
    unsigned short* eb0 = (unsigned short*)(ws + WS_EB);
    unsigned short* eb1 = (unsigned short*)(ws + WS_EB + 262144);

    k_prep_e<<<NCODES / 256, 256, 0, stream>>>(embed, cs, eb0, eb1, me2, hist, psum);
    k_argmin_mfma<<<128 * KSPLIT, 256, 0, stream>>>(z, eb0, eb1, me2, pb1g, pb2g);
    k_refine<<<NPTS / 32, 256, 0, stream>>>(z, embed, me2, pb1g, pb2g,
                                            codesi, out_codes, zq, hist, zrow);
    k_scan<<<1, 1024, 0, stream>>>(hist, boff, boff2);
    k_reorder<<<NPTS / 256, 256, 0, stream>>>(codesi, boff2, order);
    k_accum<<<NCODES / 4, 256, 0, stream>>>(hist, boff, order, zrow, cs, eavg, psum,
                                            out_ncs, out_nea, out_ne);
}

// Round 8
// 137.721 us; speedup vs baseline: 7.9430x; 1.5617x over previous
//
#include <hip/hip_runtime.h>
#include <math.h>
#include <float.h>

#define NPTS   32768
#define NCODES 8192
#define D      64
#define HWSZ   4096
#define KSPLIT 8
#define NSTAGE 8             // stages per split

#define DECAY_F 0.99f
#define OMD_F   ((float)(1.0 - 0.99))
#define EPS_F   1e-5f

typedef __attribute__((ext_vector_type(8)))  short bf16x8;
typedef __attribute__((ext_vector_type(8)))  unsigned short us8;
typedef __attribute__((ext_vector_type(4)))  float f32x4;
typedef __attribute__((ext_vector_type(16))) float f32x16;

// ---- d_out layout (floats) ----
#define ZQ_OFF    0
#define CODES_OFF 2097152
#define NE_OFF    2129920
#define NCS_OFF   2654208
#define NEA_OFF   2662400

// ---- workspace layout (floats) ----
#define WS_PSUM   0         // 64 (32 used)
#define WS_ME2    64        // 8192
#define WS_HIST   8256      // 8192 (int)
#define WS_BOFF   16448     // 8192 (int)
#define WS_BOFF2  24640     // 8192 (int)
#define WS_CODES  32832     // 32768 (int)
#define WS_ORDER  65600     // 32768 (int)
#define WS_PMG    98368     // 1048576 : per pt x split {m1, g1, m2, g2}
#define WS_EB     1146944   // 2 planes x 262144 floats (ushort data)
#define WS_ZROW   1671232   // 2097152 : z in [pt][dim] layout

__device__ __forceinline__ unsigned short f2bf(float x) {
    unsigned int u = __float_as_uint(x);
    unsigned int r = (u + 0x7fffu + ((u >> 16) & 1u)) >> 16;
    return (unsigned short)r;
}
__device__ __forceinline__ float bf2f(unsigned short b) {
    return __uint_as_float(((unsigned int)b) << 16);
}

// embed -> 2 bf16 planes (stage-blocked K-major) + me2 + hist=0 + psum
__global__ __launch_bounds__(256) void k_prep_e(
    const float* __restrict__ embed, const float* __restrict__ cs_in,
    unsigned short* __restrict__ eb0, unsigned short* __restrict__ eb1,
    float* __restrict__ me2, int* __restrict__ hist, float* __restrict__ psum)
{
    __shared__ float wsum[4];
    const int tid = threadIdx.x;
    int c = blockIdx.x * 256 + tid;
    const float4* src = (const float4*)(embed + (size_t)c * D);
    float row[64];
    float s2 = 0.f;
#pragma unroll
    for (int i = 0; i < 16; ++i) {
        float4 v = src[i];
        row[i * 4 + 0] = v.x; row[i * 4 + 1] = v.y;
        row[i * 4 + 2] = v.z; row[i * 4 + 3] = v.w;
        s2 += v.x * v.x; s2 += v.y * v.y; s2 += v.z * v.z; s2 += v.w * v.w;
    }
    size_t base = (size_t)(c >> 7) * 8192 + (size_t)(c & 127) * 8;
#pragma unroll
    for (int s = 0; s < 8; ++s) {
        us8 v0, v1;
#pragma unroll
        for (int j = 0; j < 8; ++j) {
            float x = row[s * 8 + j];
            unsigned short a = f2bf(x);
            float r1 = x - bf2f(a);
            v0[j] = a; v1[j] = f2bf(r1);
        }
        *(us8*)(eb0 + base + (size_t)s * 1024) = v0;
        *(us8*)(eb1 + base + (size_t)s * 1024) = v1;
    }
    me2[c] = -0.5f * s2;
    hist[c] = 0;
    float t = cs_in[c];
    t += __shfl_xor(t, 32); t += __shfl_xor(t, 16); t += __shfl_xor(t, 8);
    t += __shfl_xor(t, 4);  t += __shfl_xor(t, 2);  t += __shfl_xor(t, 1);
    if ((tid & 63) == 0) wsum[tid >> 6] = t;
    __syncthreads();
    if (tid == 0) psum[blockIdx.x] = (wsum[0] + wsum[1]) + (wsum[2] + wsum[3]);
}

#define MFMA32 __builtin_amdgcn_mfma_f32_32x32x16_bf16

#define TOP2(nt, g, gi) { \
    bool c1 = (g) > b1m[nt]; \
    bool c2 = (g) > b2m[nt]; \
    b2m[nt] = c1 ? b1m[nt] : (c2 ? (g) : b2m[nt]); \
    b2g[nt] = c1 ? b1g[nt] : (c2 ? (gi) : b2g[nt]); \
    b1m[nt] = c1 ? (g) : b1m[nt]; \
    b1g[nt] = c1 ? (gi) : b1g[nt]; }

// MFMA argmin, 32x32x16, 2-plane bf16, 3 passes (e1z0, e0z1, e0z0).
// Block = 512 pts x 1024 codes (one split). Wave = 128 pts (4 N-tiles of 32)
// -> 4 independent accumulator chains to cover MFMA latency.
__global__ __launch_bounds__(256, 2) void k_argmin_mfma(
    const float* __restrict__ z,
    const unsigned short* __restrict__ eb0, const unsigned short* __restrict__ eb1,
    const float* __restrict__ me2g,
    float* __restrict__ pmg)
{
    __shared__ unsigned short ets[2 * 8192];   // 32KB: [lvl][dchunk(8)][ci(128)][8]
    __shared__ float me2s[128];

    const int tid = threadIdx.x;
    const int l = tid & 63;
    const int w = tid >> 6;
    const int l31 = l & 31;
    const int hi = l >> 5;
    const int split = blockIdx.x >> 6;     // 0..7
    const int pgrp  = blockIdx.x & 63;     // 0..63
    const int n0    = pgrp * 512;
    const int b     = n0 >> 12;
    const int hw0   = n0 & 4095;
    const int ptw   = n0 + w * 128;

    // z fragments: 128 pts/wave (4 tiles of 32), 2 planes, 4 K-chunks
    const float* zb = z + (size_t)b * D * HWSZ;
    us8 zf[4][2][4];
#pragma unroll
    for (int nt = 0; nt < 4; ++nt) {
        const int hwp = hw0 + w * 128 + nt * 32 + l31;
#pragma unroll
        for (int kc = 0; kc < 4; ++kc) {
            us8 p0, p1;
#pragma unroll
            for (int j = 0; j < 8; ++j) {
                float x = zb[(size_t)(kc * 16 + hi * 8 + j) * HWSZ + hwp];
                unsigned short a = f2bf(x);
                float r = x - bf2f(a);
                p0[j] = a; p1[j] = f2bf(r);
            }
            zf[nt][0][kc] = p0; zf[nt][1][kc] = p1;
        }
    }

    float b1m[4], b2m[4]; int b1g[4], b2g[4];
#pragma unroll
    for (int nt = 0; nt < 4; ++nt) {
        b1m[nt] = -FLT_MAX; b2m[nt] = -FLT_MAX; b1g[nt] = 0; b2g[nt] = 0;
    }

    for (int stg = 0; stg < NSTAGE; ++stg) {
        const int sg = split * NSTAGE + stg;
        __syncthreads();
        {
            const char* s0 = (const char*)eb0 + (size_t)sg * 16384;
            const char* s1 = (const char*)eb1 + (size_t)sg * 16384;
            float4 tmp[8];
#pragma unroll
            for (int i = 0; i < 8; ++i) {
                int flat = i * 256 + tid;
                const char* sp = (flat < 1024) ? s0 : s1;
                tmp[i] = *(const float4*)(sp + (size_t)(flat & 1023) * 16);
            }
#pragma unroll
            for (int i = 0; i < 8; ++i) {
                int flat = i * 256 + tid;
                *(float4*)((char*)ets + (size_t)flat * 16) = tmp[i];
            }
            if (tid < 128) me2s[tid] = me2g[sg * 128 + tid];
        }
        __syncthreads();

#pragma unroll
        for (int ct = 0; ct < 4; ++ct) {
            f32x4 meq[4];
#pragma unroll
            for (int q = 0; q < 4; ++q)
                meq[q] = *(const f32x4*)(me2s + ct * 32 + q * 8 + hi * 4);

            f32x16 acc[4];
#pragma unroll
            for (int nt = 0; nt < 4; ++nt)
#pragma unroll
                for (int q = 0; q < 4; ++q)
#pragma unroll
                    for (int r = 0; r < 4; ++r)
                        acc[nt][q * 4 + r] = meq[q][r];

#pragma unroll
            for (int kc = 0; kc < 4; ++kc) {
                bf16x8 ea0 = *(const bf16x8*)((const char*)ets
                              + (size_t)(kc * 2 + hi) * 2048 + (size_t)(ct * 32 + l31) * 16);
                bf16x8 ea1 = *(const bf16x8*)((const char*)ets + 16384
                              + (size_t)(kc * 2 + hi) * 2048 + (size_t)(ct * 32 + l31) * 16);
                // pass e1*z0 (small cross term)
#pragma unroll
                for (int nt = 0; nt < 4; ++nt)
                    acc[nt] = MFMA32(ea1, (bf16x8)zf[nt][0][kc], acc[nt], 0, 0, 0);
                // pass e0*z1
#pragma unroll
                for (int nt = 0; nt < 4; ++nt)
                    acc[nt] = MFMA32(ea0, (bf16x8)zf[nt][1][kc], acc[nt], 0, 0, 0);
                // pass e0*z0 (main)
#pragma unroll
                for (int nt = 0; nt < 4; ++nt)
                    acc[nt] = MFMA32(ea0, (bf16x8)zf[nt][0][kc], acc[nt], 0, 0, 0);
            }

            const int gib = sg * 32 + ct * 8 + hi;
#pragma unroll
            for (int nt = 0; nt < 4; ++nt) {
#pragma unroll
                for (int q = 0; q < 4; ++q) {
                    float g = fmaxf(fmaxf(acc[nt][4 * q + 0], acc[nt][4 * q + 1]),
                                    fmaxf(acc[nt][4 * q + 2], acc[nt][4 * q + 3]));
                    TOP2(nt, g, gib + q * 2)
                }
            }
        }
    }

    // merge hi halves (point pt's codes are split across lanes l31 and l31+32)
#pragma unroll
    for (int nt = 0; nt < 4; ++nt) {
        float o1 = __shfl_xor(b1m[nt], 32); int o1g = __shfl_xor(b1g[nt], 32);
        float o2 = __shfl_xor(b2m[nt], 32); int o2g = __shfl_xor(b2g[nt], 32);
        float n1m, n2m; int n1g, n2g;
        if (o1 > b1m[nt]) {
            n1m = o1; n1g = o1g;
            if (b1m[nt] >= o2) { n2m = b1m[nt]; n2g = b1g[nt]; } else { n2m = o2; n2g = o2g; }
        } else {
            n1m = b1m[nt]; n1g = b1g[nt];
            if (o1 >= b2m[nt]) { n2m = o1; n2g = o1g; } else { n2m = b2m[nt]; n2g = b2g[nt]; }
        }
        b1m[nt] = n1m; b1g[nt] = n1g; b2m[nt] = n2m; b2g[nt] = n2g;
    }
    if (l < 32) {
#pragma unroll
        for (int nt = 0; nt < 4; ++nt) {
            int pt = ptw + nt * 32 + l31;
            float4 v = {b1m[nt], __int_as_float(b1g[nt]), b2m[nt], __int_as_float(b2g[nt])};
            *(float4*)(pmg + (size_t)pt * 32 + split * 4) = v;
        }
    }
}

// Global top-2 group merge + exact fp32 rescore of 8 candidates.
// Block = 32 points x 8 subtasks; subtask s scores code (s<4 ? G1 : G2)*4 + (s&3).
__global__ __launch_bounds__(256) void k_refine(
    const float* __restrict__ z, const float* __restrict__ embed,
    const float* __restrict__ me2, const float* __restrict__ pmg,
    int* __restrict__ codes_i, float* __restrict__ out_codes,
    float* __restrict__ zq, int* __restrict__ hist, float* __restrict__ zrow)
{
    __shared__ float  xs[64 * 32];    // [dim][pt]
    __shared__ float4 smg[256];       // transposed: [split j][pt]
    __shared__ float  sbm[256];
    __shared__ int    sbi[256];
    const int tid = threadIdx.x;
    const int pi = tid & 31, s = tid >> 5;
    const int n0 = blockIdx.x * 32;
    const int b = n0 >> 12, hw0 = n0 & 4095;
    const int n = n0 + pi;

    {
        float4 v = *((const float4*)pmg + (size_t)n0 * 8 + tid);
        smg[(tid & 7) * 32 + (tid >> 3)] = v;
    }
    const float* zb = z + (size_t)b * D * HWSZ + hw0;
#pragma unroll
    for (int i = 0; i < 8; ++i) {
        int c = s * 8 + i;
        xs[c * 32 + pi] = zb[(size_t)c * HWSZ + pi];
    }
    __syncthreads();
    float x[64];
#pragma unroll
    for (int c = 0; c < 64; ++c) x[c] = xs[c * 32 + pi];

    // merge 8 splits x (top1, top2) -> global top-2 groups
    float t1 = -FLT_MAX, t2 = -FLT_MAX; int g1 = 0, g2 = 0;
#pragma unroll
    for (int j = 0; j < 8; ++j) {
        float4 v = smg[j * 32 + pi];
        float m1 = v.x; int a1 = __float_as_int(v.y);
        float m2 = v.z; int a2 = __float_as_int(v.w);
        if (m1 > t1) { t2 = t1; g2 = g1; t1 = m1; g1 = a1; }
        else if (m1 > t2) { t2 = m1; g2 = a1; }
        if (m2 > t1) { t2 = t1; g2 = g1; t1 = m2; g1 = a2; }
        else if (m2 > t2) { t2 = m2; g2 = a2; }
    }

    const int ci = ((s < 4) ? g1 : g2) * 4 + (s & 3);
    const float4* er = (const float4*)(embed + (size_t)ci * D);
    float d0 = 0.f, d1 = 0.f, d2 = 0.f, d3 = 0.f;
#pragma unroll
    for (int q = 0; q < 16; ++q) {
        float4 e4 = er[q];
        d0 = fmaf(x[4 * q + 0], e4.x, d0);
        d1 = fmaf(x[4 * q + 1], e4.y, d1);
        d2 = fmaf(x[4 * q + 2], e4.z, d2);
        d3 = fmaf(x[4 * q + 3], e4.w, d3);
    }
    float m = ((d0 + d1) + (d2 + d3)) + me2[ci];
    sbm[tid] = m; sbi[tid] = ci;
    __syncthreads();

    if (s == 0) {
        float B = sbm[pi]; int I = sbi[pi];
#pragma unroll
        for (int t = 1; t < 8; ++t) {
            float mm = sbm[t * 32 + pi]; int ii = sbi[t * 32 + pi];
            if (mm > B || (mm == B && ii < I)) { B = mm; I = ii; }
        }
        codes_i[n] = I;
        out_codes[n] = (float)I;
        atomicAdd(&hist[I], 1);
        const float* err = embed + (size_t)I * D;
        size_t zoff = (size_t)b * D * HWSZ + hw0 + pi;
#pragma unroll 8
        for (int c = 0; c < 64; ++c) zq[zoff + (size_t)c * HWSZ] = err[c];
    }
    {
        float4 a4 = {x[s * 8 + 0], x[s * 8 + 1], x[s * 8 + 2], x[s * 8 + 3]};
        float4 b4 = {x[s * 8 + 4], x[s * 8 + 5], x[s * 8 + 6], x[s * 8 + 7]};
        *(float4*)(zrow + (size_t)n * 64 + s * 8) = a4;
        *(float4*)(zrow + (size_t)n * 64 + s * 8 + 4) = b4;
    }
}

// exclusive prefix sum of hist (8192 ints) -> binoff and binoff2
__global__ __launch_bounds__(1024) void k_scan(
    const int* __restrict__ hist, int* __restrict__ binoff, int* __restrict__ binoff2)
{
    __shared__ int wtot[16];
    __shared__ int wbase[16];
    const int tid = threadIdx.x;
    const int lane = tid & 63, w = tid >> 6;
    int v[8]; int s = 0;
#pragma unroll
    for (int i = 0; i < 8; ++i) { v[i] = hist[tid * 8 + i]; s += v[i]; }
    int inc = s;
#pragma unroll
    for (int off = 1; off < 64; off <<= 1) {
        int t = __shfl_up(inc, off);
        if (lane >= off) inc += t;
    }
    if (lane == 63) wtot[w] = inc;
    __syncthreads();
    if (tid == 0) {
        int a = 0;
#pragma unroll
        for (int i = 0; i < 16; ++i) { int t = wtot[i]; wbase[i] = a; a += t; }
    }
    __syncthreads();
    int excl = wbase[w] + (inc - s);
#pragma unroll
    for (int i = 0; i < 8; ++i) {
        binoff[tid * 8 + i] = excl;
        binoff2[tid * 8 + i] = excl;
        excl += v[i];
    }
}

// scatter point ids into code-sorted order
__global__ void k_reorder(const int* __restrict__ codes_i,
                          int* __restrict__ binoff2, int* __restrict__ order)
{
    int n = blockIdx.x * 256 + threadIdx.x;
    int c = codes_i[n];
    int r = atomicAdd(&binoff2[c], 1);
    order[r] = n;
}

// one wave per code: segmented sum over zrow + fused EMA update + normalize
__global__ __launch_bounds__(256) void k_accum(
    const int* __restrict__ hist, const int* __restrict__ binoff,
    const int* __restrict__ order, const float* __restrict__ zrow,
    const float* __restrict__ cs, const float* __restrict__ eavg,
    const float* __restrict__ psum,
    float* __restrict__ out_ncs, float* __restrict__ out_nea, float* __restrict__ out_ne)
{
    int k = blockIdx.x * 4 + (threadIdx.x >> 6);
    int lane = threadIdx.x & 63;
    int cnt = hist[k], base = binoff[k];
    float acc = 0.f;
    for (int i = 0; i < cnt; ++i) {
        int p = order[base + i];
        acc += zrow[(size_t)p * 64 + lane];
    }
    float S = 0.f;
#pragma unroll
    for (int i = 0; i < 32; ++i) S += psum[i];
    float n = DECAY_F * S + OMD_F * (float)NPTS;

    float v = cs[k] * DECAY_F + (float)cnt * OMD_F;
    if (lane == 0) out_ncs[k] = v;

    int idx = k * D + lane;
    float ea = eavg[idx] * DECAY_F + acc * OMD_F;
    out_nea[idx] = ea;
    float csm = (v + EPS_F) / (n + (float)NCODES * EPS_F) * n;
    float u = ea / csm;
    float ss = u * u;
    ss += __shfl_xor(ss, 32);
    ss += __shfl_xor(ss, 16);
    ss += __shfl_xor(ss, 8);
    ss += __shfl_xor(ss, 4);
    ss += __shfl_xor(ss, 2);
    ss += __shfl_xor(ss, 1);
    out_ne[idx] = u / sqrtf(ss);
}

extern "C" void kernel_launch(void* const* d_in, const int* in_sizes, int n_in,
                              void* d_out, int out_size, void* d_ws, size_t ws_size,
                              hipStream_t stream) {
    const float* z     = (const float*)d_in[0];
    const float* embed = (const float*)d_in[1];
    const float* cs    = (const float*)d_in[2];
    const float* eavg  = (const float*)d_in[3];

    float* out = (float*)d_out;
    float* zq        = out + ZQ_OFF;
    float* out_codes = out + CODES_OFF;
    float* out_ne    = out + NE_OFF;
    float* out_ncs   = out + NCS_OFF;
    float* out_nea   = out + NEA_OFF;

    float* ws = (float*)d_ws;
    float* psum   = ws + WS_PSUM;
    float* me2    = ws + WS_ME2;
    int*   hist   = (int*)(ws + WS_HIST);
    int*   boff   = (int*)(ws + WS_BOFF);
    int*   boff2  = (int*)(ws + WS_BOFF2);
    int*   codesi = (int*)(ws + WS_CODES);
    int*   order  = (int*)(ws + WS_ORDER);
    float* pmg    = ws + WS_PMG;
    float* zrow   = ws + WS_ZROW;
    unsigned short* eb0 = (unsigned short*)(ws + WS_EB);
    unsigned short* eb1 = (unsigned short*)(ws + WS_EB + 262144);

    k_prep_e<<<NCODES / 256, 256, 0, stream>>>(embed, cs, eb0, eb1, me2, hist, psum);
    k_argmin_mfma<<<64 * KSPLIT, 256, 0, stream>>>(z, eb0, eb1, me2, pmg);
    k_refine<<<NPTS / 32, 256, 0, stream>>>(z, embed, me2, pmg,
                                            codesi, out_codes, zq, hist, zrow);
    k_scan<<<1, 1024, 0, stream>>>(hist, boff, boff2);
    k_reorder<<<NPTS / 256, 256, 0, stream>>>(codesi, boff2, order);
    k_accum<<<NCODES / 4, 256, 0, stream>>>(hist, boff, order, zrow, cs, eavg, psum,
                                            out_ncs, out_nea, out_ne);
}